// Round 19
// baseline (1339.330 us; speedup 1.0000x reference)
//
#include <hip/hip_runtime.h>
#include <hip/hip_bf16.h>

#define C_DIM 512
#define HW    4096
#define BATCH 4
#define PW    66
#define PPIX  (PW*PW)   // 4356

typedef __attribute__((ext_vector_type(8))) short bf16x8;
typedef __attribute__((ext_vector_type(4))) float f32x4;
typedef __attribute__((ext_vector_type(16))) float f32x16;
typedef __attribute__((ext_vector_type(2))) long long l64x2;
typedef __attribute__((ext_vector_type(2))) float f32x2;

static __device__ __forceinline__ short f2b(float f) {
    union { float f; unsigned u; } v; v.f = f;
    unsigned r = v.u + 0x7fffu + ((v.u >> 16) & 1u);
    return (short)(r >> 16);
}
static __device__ __forceinline__ float b2f(short s) {
    union { unsigned u; float f; } v; v.u = ((unsigned)(unsigned short)s) << 16;
    return v.f;
}

static __device__ __forceinline__ f32x4 zero4() {
    f32x4 v = {0.f, 0.f, 0.f, 0.f};
    return v;
}
static __device__ __forceinline__ f32x16 zero16() {
    f32x16 v = {0.f,0.f,0.f,0.f, 0.f,0.f,0.f,0.f, 0.f,0.f,0.f,0.f, 0.f,0.f,0.f,0.f};
    return v;
}

static __device__ __forceinline__ void gload16(const void* g, void* l) {
    __builtin_amdgcn_global_load_lds(
        (__attribute__((address_space(1))) void*)g,
        (__attribute__((address_space(3))) void*)l, 16, 0, 0);
}

// ---------------- weight prep ----------------
// 3x3 weights float -> fp8 e4m3 x64, packed rows of 4608 bytes (see r13)
__global__ void k_reorder_w38(const float* __restrict__ w, unsigned char* __restrict__ out) {
    int i = blockIdx.x * 256 + threadIdx.x;
    int o = i / 576;
    int p8 = (i - o * 576) * 8;
    int kc2 = p8 >> 6;
    int tap = kc2 >> 3;
    int p = p8 & 63;
    int g = (p >> 4) & 3, half = (p >> 3) & 1;
    int c0 = (kc2 & 7) * 64 + half * 32 + g * 8;
    const float* src = w + ((size_t)o * 512 + c0) * 9 + tap;
    float f0 = src[0] * 64.f, f1 = src[9] * 64.f, f2 = src[18] * 64.f, f3 = src[27] * 64.f;
    float f4 = src[36] * 64.f, f5 = src[45] * 64.f, f6 = src[54] * 64.f, f7 = src[63] * 64.f;
    int lo = __builtin_amdgcn_cvt_pk_fp8_f32(f0, f1, 0, false);
    lo     = __builtin_amdgcn_cvt_pk_fp8_f32(f2, f3, lo, true);
    int hi = __builtin_amdgcn_cvt_pk_fp8_f32(f4, f5, 0, false);
    hi     = __builtin_amdgcn_cvt_pk_fp8_f32(f6, f7, hi, true);
    *(uint2*)&out[(size_t)o * 4608 + p8] = make_uint2((unsigned)lo, (unsigned)hi);
}

// 1x1 weights float -> fp8 e4m3 x64, packed rows of 512 bytes (verified r14/r16)
__global__ void k_reorder_w18(const float* __restrict__ w, unsigned char* __restrict__ out) {
    int i = blockIdx.x * 256 + threadIdx.x;
    int o = i >> 6;
    int p8 = (i & 63) * 8;
    int grp = p8 >> 6;
    int p = p8 & 63;
    int g = (p >> 4) & 3, half = (p >> 3) & 1;
    int c0 = grp * 64 + half * 32 + g * 8;
    const float* src = w + (size_t)o * 512 + c0;
    int lo = __builtin_amdgcn_cvt_pk_fp8_f32(src[0] * 64.f, src[1] * 64.f, 0, false);
    lo     = __builtin_amdgcn_cvt_pk_fp8_f32(src[2] * 64.f, src[3] * 64.f, lo, true);
    int hi = __builtin_amdgcn_cvt_pk_fp8_f32(src[4] * 64.f, src[5] * 64.f, 0, false);
    hi     = __builtin_amdgcn_cvt_pk_fp8_f32(src[6] * 64.f, src[7] * 64.f, hi, true);
    *(uint2*)&out[(size_t)o * 512 + p8] = make_uint2((unsigned)lo, (unsigned)hi);
}

// K bf16 -> fp8 e4m3, with kc-pair byte permutation (see r8)
__global__ void k_cvt_k8(const short* __restrict__ in, unsigned char* __restrict__ out) {
    int i = blockIdx.x * 256 + threadIdx.x;
    int m = i >> 6;
    int p = (i & 63) * 8;
    int kcp = p >> 6, g = (p >> 4) & 3, half = (p >> 3) & 1;
    int chb = (kcp * 2 + half) * 32 + g * 8;
    bf16x8 v = *(const bf16x8*)&in[(size_t)m * 512 + chb];
    int lo = __builtin_amdgcn_cvt_pk_fp8_f32(b2f(v[0]), b2f(v[1]), 0, false);
    lo     = __builtin_amdgcn_cvt_pk_fp8_f32(b2f(v[2]), b2f(v[3]), lo, true);
    int hi = __builtin_amdgcn_cvt_pk_fp8_f32(b2f(v[4]), b2f(v[5]), 0, false);
    hi     = __builtin_amdgcn_cvt_pk_fp8_f32(b2f(v[6]), b2f(v[7]), hi, true);
    *(uint2*)&out[(size_t)m * 512 + p] = make_uint2((unsigned)lo, (unsigned)hi);
}

// ---------------- fused layernorm -> packed fp8 hp8 (r15/r16, unchanged) -------
__global__ void k_ln_fused(const float* __restrict__ x, const float* __restrict__ lnw,
                           const float* __restrict__ lnb, unsigned char* __restrict__ hp8) {
    __shared__ float red[8][64];
    __shared__ float mean_s[64], rstd_s[64];
    __shared__ short tile[64][65];
    int bid = blockIdx.x;
    int y = bid & 63, b = bid >> 6;
    int t = threadIdx.x;
    int px = t & 63, cg = t >> 6;
    const float* xb = x + (size_t)b * C_DIM * HW + (size_t)y * 64;

    float s = 0.f, sq = 0.f;
    for (int c = cg * 128; c < cg * 128 + 128; ++c) {
        float v = xb[(size_t)c * HW + px];
        s += v; sq += v * v;
    }
    red[cg][px] = s;
    red[4 + cg][px] = sq;
    __syncthreads();
    if (t < 64) {
        float S = red[0][t] + red[1][t] + red[2][t] + red[3][t];
        float Q = red[4][t] + red[5][t] + red[6][t] + red[7][t];
        float mu  = S * (1.0f / C_DIM);
        float var = Q * (1.0f / C_DIM) - mu * mu;
        mean_s[t] = mu;
        rstd_s[t] = 1.0f / sqrtf(var + 1e-6f);
    }
    __syncthreads();
    float mu = mean_s[px], rs = rstd_s[px];
    int chn = t & 7, pxe = t >> 3;
    int clocal = (chn & 1) * 32 + ((chn >> 1) & 3) * 8;
    for (int ct = 0; ct < 8; ++ct) {
        int c0 = ct * 64;
        #pragma unroll
        for (int cc = 0; cc < 64; cc += 4) {
            int c = c0 + cc + cg;
            float v = xb[(size_t)c * HW + px];
            tile[cc + cg][px] = f2b((v - mu) * rs * lnw[c] + lnb[c]);
        }
        __syncthreads();
        #pragma unroll
        for (int h = 0; h < 2; ++h) {
            int pix = pxe + h * 32;
            float f0 = b2f(tile[clocal + 0][pix]);
            float f1 = b2f(tile[clocal + 1][pix]);
            float f2 = b2f(tile[clocal + 2][pix]);
            float f3 = b2f(tile[clocal + 3][pix]);
            float f4 = b2f(tile[clocal + 4][pix]);
            float f5 = b2f(tile[clocal + 5][pix]);
            float f6 = b2f(tile[clocal + 6][pix]);
            float f7 = b2f(tile[clocal + 7][pix]);
            int lo = __builtin_amdgcn_cvt_pk_fp8_f32(f0, f1, 0, false);
            lo     = __builtin_amdgcn_cvt_pk_fp8_f32(f2, f3, lo, true);
            int hi = __builtin_amdgcn_cvt_pk_fp8_f32(f4, f5, 0, false);
            hi     = __builtin_amdgcn_cvt_pk_fp8_f32(f6, f7, hi, true);
            size_t row = (size_t)b * PPIX + (size_t)(y + 1) * PW + 1 + pix;
            *(uint2*)&hp8[row * 512 + c0 + chn * 8] = make_uint2((unsigned)lo, (unsigned)hi);
        }
        __syncthreads();
    }
}

// ---------------- fused K+V 3x3 conv, fp8; V output packed fp8 (r18) -----------
__global__ __launch_bounds__(256, 2) void k_gemm_kv8(
        const unsigned char* __restrict__ A8, const unsigned char* __restrict__ Bk8,
        const unsigned char* __restrict__ Bv8, short* __restrict__ OutK,
        unsigned char* __restrict__ OutV8)
{
    __shared__ unsigned char Alds[2][10240];
    __shared__ unsigned char Bklds[2][10240];
    __shared__ unsigned char Bvlds[2][10240];
    int bid = blockIdx.x;
    int mt = bid & 31, nt = (bid >> 5) & 3, b = bid >> 7;
    int m0 = mt * 128, n0 = nt * 128;
    int t = threadIdx.x;
    int lane = t & 63, w = t >> 6;
    int wm = w >> 1, wn = w & 1;
    int g = lane >> 4, li = lane & 15;
    const unsigned char* Ab = A8 + (size_t)b * PPIX * 512;

    int srowv[3], schv[3];
    #pragma unroll
    for (int r = 0; r < 3; ++r) {
        int slot = r * 256 + t;
        int row = slot / 5;
        int ch = slot - row * 5;
        srowv[r] = row;
        schv[r] = (ch < 4) ? ch * 16 : 0;
    }
    bool act2 = (w < 2);

    f32x4 accK[4][4], accV[4][4];
    #pragma unroll
    for (int i = 0; i < 4; ++i)
        #pragma unroll
        for (int j = 0; j < 4; ++j) { accK[i][j] = zero4(); accV[i][j] = zero4(); }

    auto STAGE = [&](int bf, int kc2) {
        int tap = kc2 >> 3;
        int gofs = (kc2 & 7) * 64;
        int ty3 = tap / 3, tx3 = tap % 3;
        #pragma unroll
        for (int r = 0; r < 3; ++r) {
            if (r < 2 || act2) {
                int row = srowv[r];
                int m = m0 + row;
                int yy = m >> 6, xx = m & 63;
                int pp = (yy + ty3) * PW + xx + tx3;
                int dst = (r * 256 + t) * 16;
                gload16(Ab + (size_t)pp * 512 + gofs + schv[r], &Alds[bf][dst]);
                size_t gb = (size_t)(n0 + row) * 4608 + kc2 * 64 + schv[r];
                gload16(Bk8 + gb, &Bklds[bf][dst]);
                gload16(Bv8 + gb, &Bvlds[bf][dst]);
            }
        }
    };

    auto COMPUTE = [&](int bf) {
        l64x2 av[4], bk[4], bv[4];
        #pragma unroll
        for (int i = 0; i < 4; ++i)
            av[i] = *(const l64x2*)&Alds[bf][(wm * 64 + i * 16 + li) * 80 + g * 16];
        #pragma unroll
        for (int j = 0; j < 4; ++j)
            bk[j] = *(const l64x2*)&Bklds[bf][(wn * 64 + j * 16 + li) * 80 + g * 16];
        #pragma unroll
        for (int j = 0; j < 4; ++j)
            bv[j] = *(const l64x2*)&Bvlds[bf][(wn * 64 + j * 16 + li) * 80 + g * 16];
        #pragma unroll
        for (int h = 0; h < 2; ++h) {
            #pragma unroll
            for (int i = 0; i < 4; ++i)
                #pragma unroll
                for (int j = 0; j < 4; ++j)
                    accK[i][j] = __builtin_amdgcn_mfma_f32_16x16x32_fp8_fp8(
                        av[i][h], bk[j][h], accK[i][j], 0, 0, 0);
            #pragma unroll
            for (int i = 0; i < 4; ++i)
                #pragma unroll
                for (int j = 0; j < 4; ++j)
                    accV[i][j] = __builtin_amdgcn_mfma_f32_16x16x32_fp8_fp8(
                        av[i][h], bv[j][h], accV[i][j], 0, 0, 0);
        }
    };

    STAGE(0, 0);
    __syncthreads();
    int bf = 0;
    for (int kc2 = 0; kc2 < 72; ++kc2) {
        if (kc2 + 1 < 72) STAGE(bf ^ 1, kc2 + 1);
        COMPUTE(bf);
        __syncthreads();
        bf ^= 1;
    }

    const float SCL = 0.015625f;   // 1/64
    #pragma unroll
    for (int fm = 0; fm < 4; ++fm) {
        #pragma unroll
        for (int fn = 0; fn < 4; ++fn) {
            int mrow = m0 + wm * 64 + fm * 16 + g * 4;
            int ncol = n0 + wn * 64 + fn * 16 + li;
            #pragma unroll
            for (int i = 0; i < 4; ++i) {
                size_t dst = ((size_t)b * HW + mrow + i) * C_DIM + ncol;
                OutK[dst] = f2b(accK[fm][fn][i] * SCL);
            }
            size_t dstv = ((size_t)b * C_DIM + ncol) * HW + mrow;
            int pk = __builtin_amdgcn_cvt_pk_fp8_f32(accV[fm][fn][0] * SCL,
                                                     accV[fm][fn][1] * SCL, 0, false);
            pk     = __builtin_amdgcn_cvt_pk_fp8_f32(accV[fm][fn][2] * SCL,
                                                     accV[fm][fn][3] * SCL, pk, true);
            *(unsigned*)&OutV8[dstv] = (unsigned)pk;
        }
    }
}

// ---------------- q 1x1 conv, fp8 (r16, unchanged) ----------------
__global__ __launch_bounds__(256, 2) void k_gemm_q8(
        const unsigned char* __restrict__ A8, const unsigned char* __restrict__ Bq8,
        short* __restrict__ OutQ)
{
    __shared__ unsigned char Alds[2][10240];
    __shared__ unsigned char Blds[2][10240];
    int bid = blockIdx.x;
    int mt = bid & 31, nt = (bid >> 5) & 3, b = bid >> 7;
    int m0 = mt * 128, n0 = nt * 128;
    int t = threadIdx.x;
    int lane = t & 63, w = t >> 6;
    int wm = w >> 1, wn = w & 1;
    int g = lane >> 4, li = lane & 15;
    const unsigned char* Ab = A8 + (size_t)b * PPIX * 512;

    int srowv[3], schv[3];
    #pragma unroll
    for (int r = 0; r < 3; ++r) {
        int slot = r * 256 + t;
        int row = slot / 5;
        int ch = slot - row * 5;
        srowv[r] = row;
        schv[r] = (ch < 4) ? ch * 16 : 0;
    }
    bool act2 = (w < 2);

    f32x4 accQ[4][4];
    #pragma unroll
    for (int i = 0; i < 4; ++i)
        #pragma unroll
        for (int j = 0; j < 4; ++j) accQ[i][j] = zero4();

    auto STAGE = [&](int bf, int kc2) {
        int gofs = kc2 * 64;
        #pragma unroll
        for (int r = 0; r < 3; ++r) {
            if (r < 2 || act2) {
                int row = srowv[r];
                int m = m0 + row;
                int yy = m >> 6, xx = m & 63;
                int pp = (yy + 1) * PW + xx + 1;
                int dst = (r * 256 + t) * 16;
                gload16(Ab + (size_t)pp * 512 + gofs + schv[r], &Alds[bf][dst]);
                gload16(Bq8 + (size_t)(n0 + row) * 512 + gofs + schv[r], &Blds[bf][dst]);
            }
        }
    };

    auto COMPUTE = [&](int bf) {
        l64x2 av[4], bq[4];
        #pragma unroll
        for (int i = 0; i < 4; ++i)
            av[i] = *(const l64x2*)&Alds[bf][(wm * 64 + i * 16 + li) * 80 + g * 16];
        #pragma unroll
        for (int j = 0; j < 4; ++j)
            bq[j] = *(const l64x2*)&Blds[bf][(wn * 64 + j * 16 + li) * 80 + g * 16];
        #pragma unroll
        for (int h = 0; h < 2; ++h)
            #pragma unroll
            for (int i = 0; i < 4; ++i)
                #pragma unroll
                for (int j = 0; j < 4; ++j)
                    accQ[i][j] = __builtin_amdgcn_mfma_f32_16x16x32_fp8_fp8(
                        av[i][h], bq[j][h], accQ[i][j], 0, 0, 0);
    };

    STAGE(0, 0);
    __syncthreads();
    int bf = 0;
    for (int kc2 = 0; kc2 < 8; ++kc2) {
        if (kc2 + 1 < 8) STAGE(bf ^ 1, kc2 + 1);
        COMPUTE(bf);
        __syncthreads();
        bf ^= 1;
    }

    const float SCL = 0.015625f;
    #pragma unroll
    for (int fm = 0; fm < 4; ++fm) {
        #pragma unroll
        for (int fn = 0; fn < 4; ++fn) {
            int mrow = m0 + wm * 64 + fm * 16 + g * 4;
            int ncol = n0 + wn * 64 + fn * 16 + li;
            #pragma unroll
            for (int i = 0; i < 4; ++i) {
                size_t dst = ((size_t)b * HW + mrow + i) * C_DIM + ncol;
                OutQ[dst] = f2b(accQ[fm][fn][i] * SCL);
            }
        }
    }
}

// ---------------- proj 1x1 conv, fp8 (r17, unchanged) ----------------
__global__ __launch_bounds__(256, 2) void k_gemm_p8(
        const unsigned char* __restrict__ A8, const unsigned char* __restrict__ Bp8,
        float* __restrict__ Out, const float* __restrict__ bias,
        const float* __restrict__ resid)
{
    __shared__ unsigned char Alds[2][10240];
    __shared__ unsigned char Blds[2][10240];
    int bid = blockIdx.x;
    int mt = bid & 31, nt = (bid >> 5) & 3, b = bid >> 7;
    int m0 = mt * 128, n0 = nt * 128;
    int t = threadIdx.x;
    int lane = t & 63, w = t >> 6;
    int wm = w >> 1, wn = w & 1;
    int g = lane >> 4, li = lane & 15;
    const unsigned char* Ab = A8 + (size_t)b * HW * 512;

    int srowv[3], schv[3];
    #pragma unroll
    for (int r = 0; r < 3; ++r) {
        int slot = r * 256 + t;
        int row = slot / 5;
        int ch = slot - row * 5;
        srowv[r] = row;
        schv[r] = (ch < 4) ? ch * 16 : 0;
    }
    bool act2 = (w < 2);

    f32x4 acc[4][4];
    #pragma unroll
    for (int i = 0; i < 4; ++i)
        #pragma unroll
        for (int j = 0; j < 4; ++j) acc[i][j] = zero4();

    auto STAGE = [&](int bf, int kc2) {
        int gofs = kc2 * 64;
        #pragma unroll
        for (int r = 0; r < 3; ++r) {
            if (r < 2 || act2) {
                int row = srowv[r];
                int dst = (r * 256 + t) * 16;
                gload16(Ab + (size_t)(m0 + row) * 512 + gofs + schv[r], &Alds[bf][dst]);
                gload16(Bp8 + (size_t)(n0 + row) * 512 + gofs + schv[r], &Blds[bf][dst]);
            }
        }
    };

    auto COMPUTE = [&](int bf) {
        l64x2 av[4], bp[4];
        #pragma unroll
        for (int i = 0; i < 4; ++i)
            av[i] = *(const l64x2*)&Alds[bf][(wm * 64 + i * 16 + li) * 80 + g * 16];
        #pragma unroll
        for (int j = 0; j < 4; ++j)
            bp[j] = *(const l64x2*)&Blds[bf][(wn * 64 + j * 16 + li) * 80 + g * 16];
        #pragma unroll
        for (int h = 0; h < 2; ++h)
            #pragma unroll
            for (int i = 0; i < 4; ++i)
                #pragma unroll
                for (int j = 0; j < 4; ++j)
                    acc[i][j] = __builtin_amdgcn_mfma_f32_16x16x32_fp8_fp8(
                        av[i][h], bp[j][h], acc[i][j], 0, 0, 0);
    };

    STAGE(0, 0);
    __syncthreads();
    int bf = 0;
    for (int kc2 = 0; kc2 < 8; ++kc2) {
        if (kc2 + 1 < 8) STAGE(bf ^ 1, kc2 + 1);
        COMPUTE(bf);
        __syncthreads();
        bf ^= 1;
    }

    const float SCL = 0.015625f;
    #pragma unroll
    for (int fm = 0; fm < 4; ++fm) {
        #pragma unroll
        for (int fn = 0; fn < 4; ++fn) {
            int mrow = m0 + wm * 64 + fm * 16 + g * 4;
            int ncol = n0 + wn * 64 + fn * 16 + li;
            size_t dst = ((size_t)b * C_DIM + ncol) * HW + mrow;
            float bb = bias[ncol];
            float4 xr = *(const float4*)(resid + dst);
            float4 o;
            o.x = acc[fm][fn][0] * SCL + bb + xr.x;
            o.y = acc[fm][fn][1] * SCL + bb + xr.y;
            o.z = acc[fm][fn][2] * SCL + bb + xr.z;
            o.w = acc[fm][fn][3] * SCL + bb + xr.w;
            *(float4*)(Out + dst) = o;
        }
    }
}

// ---------------- flash attention, round 19: V direct global->reg --------------
// QB=64, 4 waves, grid 512. LDS 37KB (K fp8 dbuf 32K + P 5K) -> up to 4
// blocks/CU (launch_bounds(256,4), VGPR cap 128). V is read once per block ->
// no LDS staging: 8B/lane contiguous global loads (L2-resident slice) issued at
// tile top, converted fp8->bf16 in regs at PV. Epilogue transpose in two
// ch-half passes through the pool (74-short rows).
#define KT 32
#define NTILES 64
__global__ __launch_bounds__(256, 4) void k_attn(
        const short* __restrict__ qT, const unsigned char* __restrict__ kT8,
        const unsigned char* __restrict__ vg8, short* __restrict__ O0,
        short* __restrict__ O1, float* __restrict__ L0, float* __restrict__ L1)
{
    __shared__ __align__(16) short pool[18944];     // 37888 B
    unsigned char* Kp8 = (unsigned char*)pool;      // 2 x 16384 B
    short* Pp = pool + 16384;                       // byte 32768: 64 x 40 shorts

    int bid0 = blockIdx.x;
    int bid = (bid0 & 7) * 64 + (bid0 >> 3);        // XCD swizzle: one (b,ks) per XCD
    int qt = bid & 63, ks = (bid >> 6) & 1, b = bid >> 7;
    int m0 = qt * 64;
    int t = threadIdx.x, lane = t & 63, w = t >> 6; // w: 0..3
    int g = lane >> 4, li = lane & 15;
    int l31 = lane & 31, l5 = lane >> 5;

    const unsigned char* kb8 = kT8 + ((size_t)b * HW + (size_t)ks * 2048) * 512;
    const unsigned char* vb8 = vg8 + (size_t)b * C_DIM * HW + ks * 2048;

    long long qf8[16];
    {
        const short* qrow = qT + ((size_t)b * HW + m0 + w * 16 + li) * C_DIM;
        #pragma unroll
        for (int kc = 0; kc < 16; ++kc) {
            bf16x8 qv = *(const bf16x8*)&qrow[kc * 32 + g * 8];
            int lo = __builtin_amdgcn_cvt_pk_fp8_f32(b2f(qv[0]), b2f(qv[1]), 0, false);
            lo     = __builtin_amdgcn_cvt_pk_fp8_f32(b2f(qv[2]), b2f(qv[3]), lo, true);
            int hi = __builtin_amdgcn_cvt_pk_fp8_f32(b2f(qv[4]), b2f(qv[5]), 0, false);
            hi     = __builtin_amdgcn_cvt_pk_fp8_f32(b2f(qv[6]), b2f(qv[7]), hi, true);
            qf8[kc] = ((long long)(unsigned)hi << 32) | (unsigned)lo;
        }
    }
    f32x16 oacc[8];   // [q2*4 + cht]
    #pragma unroll
    for (int a = 0; a < 8; ++a) oacc[a] = zero16();
    float lsum = 0.f;

    // K staging (chunk-transposed, as r18)
    const unsigned char* ksrc8 = kb8 + (size_t)(t & 31) * 512 + (t >> 5) * 16;
    // V per-lane fragment base: ch = w*128 + cht*32 + l31, 8B at kx*16 + l5*8
    const unsigned char* vlane8 = vb8 + (size_t)(w * 128 + l31) * 4096 + l5 * 8;

    const float SC = 0.044194173824159216f * 1.4426950408889634f;

    auto KSTAGE = [&](int buf, int nt) {
        const unsigned char* kS = ksrc8 + (size_t)(nt * KT) * 512;
        unsigned char* kD = Kp8 + buf * 16384 + t * 16;
        #pragma unroll
        for (int r = 0; r < 4; ++r)
            gload16(kS + r * 128, kD + r * 4096);
    };

    KSTAGE(0, 0);
    asm volatile("s_waitcnt vmcnt(0)" ::: "memory");
    __builtin_amdgcn_s_barrier();
    __builtin_amdgcn_sched_barrier(0);

    int buf = 0;
    for (int nt = 0; nt < NTILES; ++nt) {
        int n0 = nt * KT;
        // V fragment loads for THIS tile (global->reg, L2-resident; consumed in PV)
        long long vreg[4][2];
        #pragma unroll
        for (int cht = 0; cht < 4; ++cht)
            #pragma unroll
            for (int kx = 0; kx < 2; ++kx)
                vreg[cht][kx] = *(const long long*)&vlane8[(size_t)cht * 32 * 4096 + n0 + kx * 16];

        if (nt + 1 < NTILES) KSTAGE(buf ^ 1, nt + 1);   // K prefetch: drains at tile-end

        // ---- QK fp8 (16x16x32, swapped mfma(K,Q)) ----
        const unsigned char* kbase8 = Kp8 + buf * 16384 + g * 512 + li * 16;
        f32x4 s0[2], s1[2];
        s0[0] = zero4(); s0[1] = zero4(); s1[0] = zero4(); s1[1] = zero4();
        __builtin_amdgcn_s_setprio(1);
        #pragma unroll
        for (int kcp = 0; kcp < 8; ++kcp) {
            #pragma unroll
            for (int fn = 0; fn < 2; ++fn) {
                l64x2 kv = *(const l64x2*)&kbase8[kcp * 2048 + fn * 256];
                s0[fn] = __builtin_amdgcn_mfma_f32_16x16x32_fp8_fp8(kv[0], qf8[2 * kcp],     s0[fn], 0, 0, 0);
                s1[fn] = __builtin_amdgcn_mfma_f32_16x16x32_fp8_fp8(kv[1], qf8[2 * kcp + 1], s1[fn], 0, 0, 0);
            }
        }
        __builtin_amdgcn_s_setprio(0);
        #pragma unroll
        for (int fn = 0; fn < 2; ++fn) {
            float e0 = exp2f((s0[fn][0] + s1[fn][0]) * SC);
            float e1 = exp2f((s0[fn][1] + s1[fn][1]) * SC);
            float e2 = exp2f((s0[fn][2] + s1[fn][2]) * SC);
            float e3 = exp2f((s0[fn][3] + s1[fn][3]) * SC);
            lsum += (e0 + e1) + (e2 + e3);
            union { __hip_bfloat162 h; unsigned u; } p01, p23;
            p01.h = __float22bfloat162_rn(make_float2(e0, e1));
            p23.h = __float22bfloat162_rn(make_float2(e2, e3));
            *(uint2*)&Pp[(w * 16 + li) * 40 + fn * 16 + g * 4] = make_uint2(p01.u, p23.u);
        }

        // mid-tile barrier: P visible (LDS-only wait; K prefetch stays in flight)
        asm volatile("s_waitcnt lgkmcnt(0)" ::: "memory");
        __builtin_amdgcn_s_barrier();
        __builtin_amdgcn_sched_barrier(0);

        // ---- PV (32x32x16 bf16): C[ch][q] += V[ch][k] * P[q][k] ----
        bf16x8 pf[2][2];
        #pragma unroll
        for (int q2 = 0; q2 < 2; ++q2)
            #pragma unroll
            for (int kx = 0; kx < 2; ++kx)
                pf[q2][kx] = *(const bf16x8*)&Pp[(q2 * 32 + l31) * 40 + kx * 16 + l5 * 8];
        __builtin_amdgcn_s_setprio(1);
        #pragma unroll
        for (int cht = 0; cht < 4; ++cht) {
            bf16x8 vfb[2];
            #pragma unroll
            for (int kx = 0; kx < 2; ++kx) {
                long long v8 = vreg[cht][kx];
                unsigned lo32 = (unsigned)(unsigned long long)v8;
                unsigned hi32 = (unsigned)((unsigned long long)v8 >> 32);
                f32x2 f01 = __builtin_amdgcn_cvt_pk_f32_fp8(lo32, false);
                f32x2 f23 = __builtin_amdgcn_cvt_pk_f32_fp8(lo32, true);
                f32x2 f45 = __builtin_amdgcn_cvt_pk_f32_fp8(hi32, false);
                f32x2 f67 = __builtin_amdgcn_cvt_pk_f32_fp8(hi32, true);
                union { __hip_bfloat162 h; unsigned u; } b01, b23, b45, b67;
                b01.h = __float22bfloat162_rn(make_float2(f01[0], f01[1]));
                b23.h = __float22bfloat162_rn(make_float2(f23[0], f23[1]));
                b45.h = __float22bfloat162_rn(make_float2(f45[0], f45[1]));
                b67.h = __float22bfloat162_rn(make_float2(f67[0], f67[1]));
                union { bf16x8 v; unsigned u[4]; } vv;
                vv.u[0] = b01.u; vv.u[1] = b23.u; vv.u[2] = b45.u; vv.u[3] = b67.u;
                vfb[kx] = vv.v;
            }
            #pragma unroll
            for (int q2 = 0; q2 < 2; ++q2)
                #pragma unroll
                for (int kx = 0; kx < 2; ++kx)
                    oacc[q2 * 4 + cht] = __builtin_amdgcn_mfma_f32_32x32x16_bf16(
                        vfb[kx], pf[q2][kx], oacc[q2 * 4 + cht], 0, 0, 0);
        }
        __builtin_amdgcn_s_setprio(0);

        // tile-end barrier: K prefetch drained; Pp consumed by all waves
        asm volatile("s_waitcnt vmcnt(0)" ::: "memory");
        __builtin_amdgcn_s_barrier();
        __builtin_amdgcn_sched_barrier(0);
        buf ^= 1;
    }

    lsum += __shfl_xor(lsum, 16);
    lsum += __shfl_xor(lsum, 32);
    float* Lb = (ks ? L1 : L0) + (size_t)b * HW + m0 + w * 16;
    if (lane < 16) Lb[lane] = lsum;

    // O epilogue: two ch-half passes through the pool (64 q x 74-short rows/wave)
    short* Ob = (ks ? O1 : O0) + ((size_t)b * HW + m0) * C_DIM + w * 128;
    short* tp = pool + w * 4736;
    #pragma unroll
    for (int p = 0; p < 2; ++p) {
        __syncthreads();     // pool free (prev pass / main loop fully consumed)
        #pragma unroll
        for (int cl = 0; cl < 2; ++cl) {
            int cht = p * 2 + cl;
            #pragma unroll
            for (int q2 = 0; q2 < 2; ++q2) {
                int a = q2 * 4 + cht;
                int q_l = q2 * 32 + l31;
                #pragma unroll
                for (int rq = 0; rq < 4; ++rq) {
                    int chb = cl * 32 + rq * 8 + l5 * 4;
                    union { __hip_bfloat162 h; unsigned u; } x01, x23;
                    x01.h = __float22bfloat162_rn(make_float2(oacc[a][rq * 4 + 0], oacc[a][rq * 4 + 1]));
                    x23.h = __float22bfloat162_rn(make_float2(oacc[a][rq * 4 + 2], oacc[a][rq * 4 + 3]));
                    *(uint2*)&tp[q_l * 74 + chb] = make_uint2(x01.u, x23.u);
                }
            }
        }
        asm volatile("s_waitcnt lgkmcnt(0)" ::: "memory");
        __builtin_amdgcn_sched_barrier(0);
        #pragma unroll
        for (int qg = 0; qg < 8; ++qg) {
            int qr = qg * 8 + (lane >> 3);
            bf16x8 v = *(const bf16x8*)&tp[qr * 74 + (lane & 7) * 8];
            *(bf16x8*)&Ob[(size_t)qr * C_DIM + p * 64 + (lane & 7) * 8] = v;
        }
    }
}

// combine -> packed fp8 oatt8 (r17, unchanged)
__global__ void k_att_comb(const short* __restrict__ O0, const short* __restrict__ O1,
                           const float* __restrict__ L0, const float* __restrict__ L1,
                           unsigned char* __restrict__ oatt8) {
    int i = blockIdx.x * 256 + threadIdx.x;
    int row = i >> 6;
    int cidx = i & 63;
    int c0 = cidx * 8;
    float r = 1.0f / (L0[row] + L1[row]);
    size_t base = (size_t)row * C_DIM + c0;
    bf16x8 a = *(const bf16x8*)&O0[base];
    bf16x8 c = *(const bf16x8*)&O1[base];
    float f[8];
    #pragma unroll
    for (int j = 0; j < 8; ++j)
        f[j] = (b2f(a[j]) + b2f(c[j])) * r;
    int lo = __builtin_amdgcn_cvt_pk_fp8_f32(f[0], f[1], 0, false);
    lo     = __builtin_amdgcn_cvt_pk_fp8_f32(f[2], f[3], lo, true);
    int hi = __builtin_amdgcn_cvt_pk_fp8_f32(f[4], f[5], 0, false);
    hi     = __builtin_amdgcn_cvt_pk_fp8_f32(f[6], f[7], hi, true);
    int pbyte = (cidx >> 3) * 64 + (cidx & 3) * 16 + ((cidx >> 2) & 1) * 8;
    *(uint2*)&oatt8[(size_t)row * 512 + pbyte] = make_uint2((unsigned)lo, (unsigned)hi);
}

// ---------------- launch ----------------
extern "C" void kernel_launch(void* const* d_in, const int* in_sizes, int n_in,
                              void* d_out, int out_size, void* d_ws, size_t ws_size,
                              hipStream_t stream) {
    const float* x    = (const float*)d_in[0];
    const float* ln_w = (const float*)d_in[1];
    const float* ln_b = (const float*)d_in[2];
    const float* wq   = (const float*)d_in[3];
    const float* wk   = (const float*)d_in[4];
    const float* wv   = (const float*)d_in[5];
    const float* wp   = (const float*)d_in[6];
    const float* bp   = (const float*)d_in[7];
    float* out = (float*)d_out;

    char* ws = (char*)d_ws;
    size_t off = 0;
    auto alloc = [&](size_t bytes) {
        char* p = ws + off;
        off += (bytes + 255) & ~(size_t)255;
        return p;
    };
    short* hp   = (short*)alloc((size_t)BATCH * PPIX * C_DIM * 2);   // O-partial 0 scratch
    unsigned char* hp8 = (unsigned char*)alloc((size_t)BATCH * PPIX * 512);  // LN out; later kT8
    unsigned char* wq8 = (unsigned char*)alloc((size_t)512 * 512);
    unsigned char* wk8 = (unsigned char*)alloc((size_t)512 * 4608);
    unsigned char* wv8 = (unsigned char*)alloc((size_t)512 * 4608);
    unsigned char* wp8 = (unsigned char*)alloc((size_t)512 * 512);
    short* qT   = (short*)alloc((size_t)BATCH * HW * C_DIM * 2);
    short* kT   = (short*)alloc((size_t)BATCH * HW * C_DIM * 2);     // later oatt8
    unsigned char* vg8 = (unsigned char*)alloc((size_t)BATCH * C_DIM * HW);
    short* oatt = (short*)alloc((size_t)BATCH * HW * C_DIM * 2);     // O-partial 1
    float* mean = (float*)alloc((size_t)BATCH * HW * 4);             // Lsum 0
    float* rstd = (float*)alloc((size_t)BATCH * HW * 4);             // Lsum 1

    hipMemsetAsync(hp8, 0, (size_t)BATCH * PPIX * 512, stream);
    k_reorder_w18<<<128, 256, 0, stream>>>(wq, wq8);
    k_reorder_w18<<<128, 256, 0, stream>>>(wp, wp8);
    k_reorder_w38<<<1152, 256, 0, stream>>>(wk, wk8);
    k_reorder_w38<<<1152, 256, 0, stream>>>(wv, wv8);
    k_ln_fused<<<256, 256, 0, stream>>>(x, ln_w, ln_b, hp8);

    k_gemm_q8<<<512, 256, 0, stream>>>(hp8, wq8, qT);
    k_gemm_kv8<<<512, 256, 0, stream>>>(hp8, wk8, wv8, kT, vg8);

    // hp8 dead -> reuse as the 8MB packed fp8 K buffer
    unsigned char* kT8 = hp8;
    k_cvt_k8<<<4096, 256, 0, stream>>>(kT, kT8);

    short* Op0 = hp;
    short* Op1 = oatt;
    float* Ls0 = mean;
    float* Ls1 = rstd;
    k_attn<<<512, 256, 0, stream>>>(qT, kT8, vg8, Op0, Op1, Ls0, Ls1);

    // kT dead after cvt_k8 -> reuse as packed fp8 attention output
    unsigned char* oatt8 = (unsigned char*)kT;
    k_att_comb<<<4096, 256, 0, stream>>>(Op0, Op1, Ls0, Ls1, oatt8);

    k_gemm_p8<<<512, 256, 0, stream>>>(oatt8, wp8, out, bp, x);
}

// Round 20
// 323.770 us; speedup vs baseline: 4.1367x; 4.1367x over previous
//
#include <hip/hip_runtime.h>
#include <hip/hip_bf16.h>

#define C_DIM 512
#define HW    4096
#define BATCH 4
#define PW    66
#define PPIX  (PW*PW)   // 4356

typedef __attribute__((ext_vector_type(8))) short bf16x8;
typedef __attribute__((ext_vector_type(4))) float f32x4;
typedef __attribute__((ext_vector_type(16))) float f32x16;
typedef __attribute__((ext_vector_type(2))) long long l64x2;

static __device__ __forceinline__ short f2b(float f) {
    union { float f; unsigned u; } v; v.f = f;
    unsigned r = v.u + 0x7fffu + ((v.u >> 16) & 1u);
    return (short)(r >> 16);
}
static __device__ __forceinline__ float b2f(short s) {
    union { unsigned u; float f; } v; v.u = ((unsigned)(unsigned short)s) << 16;
    return v.f;
}

static __device__ __forceinline__ f32x4 zero4() {
    f32x4 v = {0.f, 0.f, 0.f, 0.f};
    return v;
}
static __device__ __forceinline__ f32x16 zero16() {
    f32x16 v = {0.f,0.f,0.f,0.f, 0.f,0.f,0.f,0.f, 0.f,0.f,0.f,0.f, 0.f,0.f,0.f,0.f};
    return v;
}

static __device__ __forceinline__ void gload16(const void* g, void* l) {
    __builtin_amdgcn_global_load_lds(
        (__attribute__((address_space(1))) void*)g,
        (__attribute__((address_space(3))) void*)l, 16, 0, 0);
}

// ---------------- weight prep ----------------
// 3x3 weights float -> fp8 e4m3 x64, packed rows of 4608 bytes (see r13)
__global__ void k_reorder_w38(const float* __restrict__ w, unsigned char* __restrict__ out) {
    int i = blockIdx.x * 256 + threadIdx.x;
    int o = i / 576;
    int p8 = (i - o * 576) * 8;
    int kc2 = p8 >> 6;
    int tap = kc2 >> 3;
    int p = p8 & 63;
    int g = (p >> 4) & 3, half = (p >> 3) & 1;
    int c0 = (kc2 & 7) * 64 + half * 32 + g * 8;
    const float* src = w + ((size_t)o * 512 + c0) * 9 + tap;
    float f0 = src[0] * 64.f, f1 = src[9] * 64.f, f2 = src[18] * 64.f, f3 = src[27] * 64.f;
    float f4 = src[36] * 64.f, f5 = src[45] * 64.f, f6 = src[54] * 64.f, f7 = src[63] * 64.f;
    int lo = __builtin_amdgcn_cvt_pk_fp8_f32(f0, f1, 0, false);
    lo     = __builtin_amdgcn_cvt_pk_fp8_f32(f2, f3, lo, true);
    int hi = __builtin_amdgcn_cvt_pk_fp8_f32(f4, f5, 0, false);
    hi     = __builtin_amdgcn_cvt_pk_fp8_f32(f6, f7, hi, true);
    *(uint2*)&out[(size_t)o * 4608 + p8] = make_uint2((unsigned)lo, (unsigned)hi);
}

// 1x1 weights float -> fp8 e4m3 x64, packed rows of 512 bytes (verified r14/r16)
__global__ void k_reorder_w18(const float* __restrict__ w, unsigned char* __restrict__ out) {
    int i = blockIdx.x * 256 + threadIdx.x;    // 32768 threads, 8 bytes each
    int o = i >> 6;
    int p8 = (i & 63) * 8;
    int grp = p8 >> 6;
    int p = p8 & 63;
    int g = (p >> 4) & 3, half = (p >> 3) & 1;
    int c0 = grp * 64 + half * 32 + g * 8;
    const float* src = w + (size_t)o * 512 + c0;
    int lo = __builtin_amdgcn_cvt_pk_fp8_f32(src[0] * 64.f, src[1] * 64.f, 0, false);
    lo     = __builtin_amdgcn_cvt_pk_fp8_f32(src[2] * 64.f, src[3] * 64.f, lo, true);
    int hi = __builtin_amdgcn_cvt_pk_fp8_f32(src[4] * 64.f, src[5] * 64.f, 0, false);
    hi     = __builtin_amdgcn_cvt_pk_fp8_f32(src[6] * 64.f, src[7] * 64.f, hi, true);
    *(uint2*)&out[(size_t)o * 512 + p8] = make_uint2((unsigned)lo, (unsigned)hi);
}

// K bf16 -> fp8 e4m3, with kc-pair byte permutation (see r8)
__global__ void k_cvt_k8(const short* __restrict__ in, unsigned char* __restrict__ out) {
    int i = blockIdx.x * 256 + threadIdx.x;
    int m = i >> 6;
    int p = (i & 63) * 8;
    int kcp = p >> 6, g = (p >> 4) & 3, half = (p >> 3) & 1;
    int chb = (kcp * 2 + half) * 32 + g * 8;
    bf16x8 v = *(const bf16x8*)&in[(size_t)m * 512 + chb];
    int lo = __builtin_amdgcn_cvt_pk_fp8_f32(b2f(v[0]), b2f(v[1]), 0, false);
    lo     = __builtin_amdgcn_cvt_pk_fp8_f32(b2f(v[2]), b2f(v[3]), lo, true);
    int hi = __builtin_amdgcn_cvt_pk_fp8_f32(b2f(v[4]), b2f(v[5]), 0, false);
    hi     = __builtin_amdgcn_cvt_pk_fp8_f32(b2f(v[6]), b2f(v[7]), hi, true);
    *(uint2*)&out[(size_t)m * 512 + p] = make_uint2((unsigned)lo, (unsigned)hi);
}

// ---------------- fused layernorm -> packed fp8 hp8 ----------------
__global__ void k_ln_fused(const float* __restrict__ x, const float* __restrict__ lnw,
                           const float* __restrict__ lnb, unsigned char* __restrict__ hp8) {
    __shared__ float red[8][64];
    __shared__ float mean_s[64], rstd_s[64];
    __shared__ short tile[64][65];
    int bid = blockIdx.x;
    int y = bid & 63, b = bid >> 6;
    int t = threadIdx.x;
    int px = t & 63, cg = t >> 6;
    const float* xb = x + (size_t)b * C_DIM * HW + (size_t)y * 64;

    float s = 0.f, sq = 0.f;
    for (int c = cg * 128; c < cg * 128 + 128; ++c) {
        float v = xb[(size_t)c * HW + px];
        s += v; sq += v * v;
    }
    red[cg][px] = s;
    red[4 + cg][px] = sq;
    __syncthreads();
    if (t < 64) {
        float S = red[0][t] + red[1][t] + red[2][t] + red[3][t];
        float Q = red[4][t] + red[5][t] + red[6][t] + red[7][t];
        float mu  = S * (1.0f / C_DIM);
        float var = Q * (1.0f / C_DIM) - mu * mu;
        mean_s[t] = mu;
        rstd_s[t] = 1.0f / sqrtf(var + 1e-6f);
    }
    __syncthreads();
    float mu = mean_s[px], rs = rstd_s[px];
    int chn = t & 7, pxe = t >> 3;
    int clocal = (chn & 1) * 32 + ((chn >> 1) & 3) * 8;
    for (int ct = 0; ct < 8; ++ct) {
        int c0 = ct * 64;
        #pragma unroll
        for (int cc = 0; cc < 64; cc += 4) {
            int c = c0 + cc + cg;
            float v = xb[(size_t)c * HW + px];
            tile[cc + cg][px] = f2b((v - mu) * rs * lnw[c] + lnb[c]);
        }
        __syncthreads();
        #pragma unroll
        for (int h = 0; h < 2; ++h) {
            int pix = pxe + h * 32;
            float f0 = b2f(tile[clocal + 0][pix]);
            float f1 = b2f(tile[clocal + 1][pix]);
            float f2 = b2f(tile[clocal + 2][pix]);
            float f3 = b2f(tile[clocal + 3][pix]);
            float f4 = b2f(tile[clocal + 4][pix]);
            float f5 = b2f(tile[clocal + 5][pix]);
            float f6 = b2f(tile[clocal + 6][pix]);
            float f7 = b2f(tile[clocal + 7][pix]);
            int lo = __builtin_amdgcn_cvt_pk_fp8_f32(f0, f1, 0, false);
            lo     = __builtin_amdgcn_cvt_pk_fp8_f32(f2, f3, lo, true);
            int hi = __builtin_amdgcn_cvt_pk_fp8_f32(f4, f5, 0, false);
            hi     = __builtin_amdgcn_cvt_pk_fp8_f32(f6, f7, hi, true);
            size_t row = (size_t)b * PPIX + (size_t)(y + 1) * PW + 1 + pix;
            *(uint2*)&hp8[row * 512 + c0 + chn * 8] = make_uint2((unsigned)lo, (unsigned)hi);
        }
        __syncthreads();
    }
}

// ---------------- fused K+V 3x3 conv, fp8 (r13, verified) ----------------
__global__ __launch_bounds__(256, 2) void k_gemm_kv8(
        const unsigned char* __restrict__ A8, const unsigned char* __restrict__ Bk8,
        const unsigned char* __restrict__ Bv8, short* __restrict__ OutK,
        short* __restrict__ OutV)
{
    __shared__ unsigned char Alds[2][10240];    // 128 rows x 80 B
    __shared__ unsigned char Bklds[2][10240];
    __shared__ unsigned char Bvlds[2][10240];
    int bid = blockIdx.x;
    int mt = bid & 31, nt = (bid >> 5) & 3, b = bid >> 7;
    int m0 = mt * 128, n0 = nt * 128;
    int t = threadIdx.x;
    int lane = t & 63, w = t >> 6;
    int wm = w >> 1, wn = w & 1;
    int g = lane >> 4, li = lane & 15;
    const unsigned char* Ab = A8 + (size_t)b * PPIX * 512;

    int srowv[3], schv[3];
    #pragma unroll
    for (int r = 0; r < 3; ++r) {
        int slot = r * 256 + t;
        int row = slot / 5;
        int ch = slot - row * 5;
        srowv[r] = row;
        schv[r] = (ch < 4) ? ch * 16 : 0;     // byte offset; pad loads dummy 16B
    }
    bool act2 = (w < 2);

    f32x4 accK[4][4], accV[4][4];
    #pragma unroll
    for (int i = 0; i < 4; ++i)
        #pragma unroll
        for (int j = 0; j < 4; ++j) { accK[i][j] = zero4(); accV[i][j] = zero4(); }

    auto STAGE = [&](int bf, int kc2) {
        int tap = kc2 >> 3;
        int gofs = (kc2 & 7) * 64;
        int ty3 = tap / 3, tx3 = tap % 3;
        #pragma unroll
        for (int r = 0; r < 3; ++r) {
            if (r < 2 || act2) {
                int row = srowv[r];
                int m = m0 + row;
                int yy = m >> 6, xx = m & 63;
                int pp = (yy + ty3) * PW + xx + tx3;
                int dst = (r * 256 + t) * 16;
                gload16(Ab + (size_t)pp * 512 + gofs + schv[r], &Alds[bf][dst]);
                size_t gb = (size_t)(n0 + row) * 4608 + kc2 * 64 + schv[r];
                gload16(Bk8 + gb, &Bklds[bf][dst]);
                gload16(Bv8 + gb, &Bvlds[bf][dst]);
            }
        }
    };

    auto COMPUTE = [&](int bf) {
        l64x2 av[4], bk[4], bv[4];
        #pragma unroll
        for (int i = 0; i < 4; ++i)
            av[i] = *(const l64x2*)&Alds[bf][(wm * 64 + i * 16 + li) * 80 + g * 16];
        #pragma unroll
        for (int j = 0; j < 4; ++j)
            bk[j] = *(const l64x2*)&Bklds[bf][(wn * 64 + j * 16 + li) * 80 + g * 16];
        #pragma unroll
        for (int j = 0; j < 4; ++j)
            bv[j] = *(const l64x2*)&Bvlds[bf][(wn * 64 + j * 16 + li) * 80 + g * 16];
        #pragma unroll
        for (int h = 0; h < 2; ++h) {
            #pragma unroll
            for (int i = 0; i < 4; ++i)
                #pragma unroll
                for (int j = 0; j < 4; ++j)
                    accK[i][j] = __builtin_amdgcn_mfma_f32_16x16x32_fp8_fp8(
                        av[i][h], bk[j][h], accK[i][j], 0, 0, 0);
            #pragma unroll
            for (int i = 0; i < 4; ++i)
                #pragma unroll
                for (int j = 0; j < 4; ++j)
                    accV[i][j] = __builtin_amdgcn_mfma_f32_16x16x32_fp8_fp8(
                        av[i][h], bv[j][h], accV[i][j], 0, 0, 0);
        }
    };

    STAGE(0, 0);
    __syncthreads();
    int bf = 0;
    for (int kc2 = 0; kc2 < 72; ++kc2) {
        if (kc2 + 1 < 72) STAGE(bf ^ 1, kc2 + 1);
        COMPUTE(bf);
        __syncthreads();
        bf ^= 1;
    }

    const float SCL = 0.015625f;   // 1/64 (weights were pre-scaled x64)
    #pragma unroll
    for (int fm = 0; fm < 4; ++fm) {
        #pragma unroll
        for (int fn = 0; fn < 4; ++fn) {
            int mrow = m0 + wm * 64 + fm * 16 + g * 4;
            int ncol = n0 + wn * 64 + fn * 16 + li;
            #pragma unroll
            for (int i = 0; i < 4; ++i) {
                size_t dst = ((size_t)b * HW + mrow + i) * C_DIM + ncol;
                OutK[dst] = f2b(accK[fm][fn][i] * SCL);
            }
            size_t dstv = ((size_t)b * C_DIM + ncol) * HW + mrow;
            short4 sv = make_short4(f2b(accV[fm][fn][0] * SCL), f2b(accV[fm][fn][1] * SCL),
                                    f2b(accV[fm][fn][2] * SCL), f2b(accV[fm][fn][3] * SCL));
            *(short4*)(OutV + dstv) = sv;
        }
    }
}

// ---------------- q 1x1 conv, fp8 (r16, verified) ----------------
__global__ __launch_bounds__(256, 2) void k_gemm_q8(
        const unsigned char* __restrict__ A8, const unsigned char* __restrict__ Bq8,
        short* __restrict__ OutQ)
{
    __shared__ unsigned char Alds[2][10240];
    __shared__ unsigned char Blds[2][10240];
    int bid = blockIdx.x;
    int mt = bid & 31, nt = (bid >> 5) & 3, b = bid >> 7;
    int m0 = mt * 128, n0 = nt * 128;
    int t = threadIdx.x;
    int lane = t & 63, w = t >> 6;
    int wm = w >> 1, wn = w & 1;
    int g = lane >> 4, li = lane & 15;
    const unsigned char* Ab = A8 + (size_t)b * PPIX * 512;

    int srowv[3], schv[3];
    #pragma unroll
    for (int r = 0; r < 3; ++r) {
        int slot = r * 256 + t;
        int row = slot / 5;
        int ch = slot - row * 5;
        srowv[r] = row;
        schv[r] = (ch < 4) ? ch * 16 : 0;
    }
    bool act2 = (w < 2);

    f32x4 accQ[4][4];
    #pragma unroll
    for (int i = 0; i < 4; ++i)
        #pragma unroll
        for (int j = 0; j < 4; ++j) accQ[i][j] = zero4();

    auto STAGE = [&](int bf, int kc2) {
        int gofs = kc2 * 64;
        #pragma unroll
        for (int r = 0; r < 3; ++r) {
            if (r < 2 || act2) {
                int row = srowv[r];
                int m = m0 + row;
                int yy = m >> 6, xx = m & 63;
                int pp = (yy + 1) * PW + xx + 1;     // center tap (1x1 conv)
                int dst = (r * 256 + t) * 16;
                gload16(Ab + (size_t)pp * 512 + gofs + schv[r], &Alds[bf][dst]);
                gload16(Bq8 + (size_t)(n0 + row) * 512 + gofs + schv[r], &Blds[bf][dst]);
            }
        }
    };

    auto COMPUTE = [&](int bf) {
        l64x2 av[4], bq[4];
        #pragma unroll
        for (int i = 0; i < 4; ++i)
            av[i] = *(const l64x2*)&Alds[bf][(wm * 64 + i * 16 + li) * 80 + g * 16];
        #pragma unroll
        for (int j = 0; j < 4; ++j)
            bq[j] = *(const l64x2*)&Blds[bf][(wn * 64 + j * 16 + li) * 80 + g * 16];
        #pragma unroll
        for (int h = 0; h < 2; ++h)
            #pragma unroll
            for (int i = 0; i < 4; ++i)
                #pragma unroll
                for (int j = 0; j < 4; ++j)
                    accQ[i][j] = __builtin_amdgcn_mfma_f32_16x16x32_fp8_fp8(
                        av[i][h], bq[j][h], accQ[i][j], 0, 0, 0);
    };

    STAGE(0, 0);
    __syncthreads();
    int bf = 0;
    for (int kc2 = 0; kc2 < 8; ++kc2) {
        if (kc2 + 1 < 8) STAGE(bf ^ 1, kc2 + 1);
        COMPUTE(bf);
        __syncthreads();
        bf ^= 1;
    }

    const float SCL = 0.015625f;   // 1/64
    #pragma unroll
    for (int fm = 0; fm < 4; ++fm) {
        #pragma unroll
        for (int fn = 0; fn < 4; ++fn) {
            int mrow = m0 + wm * 64 + fm * 16 + g * 4;
            int ncol = n0 + wn * 64 + fn * 16 + li;
            #pragma unroll
            for (int i = 0; i < 4; ++i) {
                size_t dst = ((size_t)b * HW + mrow + i) * C_DIM + ncol;
                OutQ[dst] = f2b(accQ[fm][fn][i] * SCL);
            }
        }
    }
}

// ---------------- proj 1x1 conv, fp8 (r17, verified) ----------------
__global__ __launch_bounds__(256, 2) void k_gemm_p8(
        const unsigned char* __restrict__ A8, const unsigned char* __restrict__ Bp8,
        float* __restrict__ Out, const float* __restrict__ bias,
        const float* __restrict__ resid)
{
    __shared__ unsigned char Alds[2][10240];
    __shared__ unsigned char Blds[2][10240];
    int bid = blockIdx.x;
    int mt = bid & 31, nt = (bid >> 5) & 3, b = bid >> 7;
    int m0 = mt * 128, n0 = nt * 128;
    int t = threadIdx.x;
    int lane = t & 63, w = t >> 6;
    int wm = w >> 1, wn = w & 1;
    int g = lane >> 4, li = lane & 15;
    const unsigned char* Ab = A8 + (size_t)b * HW * 512;

    int srowv[3], schv[3];
    #pragma unroll
    for (int r = 0; r < 3; ++r) {
        int slot = r * 256 + t;
        int row = slot / 5;
        int ch = slot - row * 5;
        srowv[r] = row;
        schv[r] = (ch < 4) ? ch * 16 : 0;
    }
    bool act2 = (w < 2);

    f32x4 acc[4][4];
    #pragma unroll
    for (int i = 0; i < 4; ++i)
        #pragma unroll
        for (int j = 0; j < 4; ++j) acc[i][j] = zero4();

    auto STAGE = [&](int bf, int kc2) {
        int gofs = kc2 * 64;
        #pragma unroll
        for (int r = 0; r < 3; ++r) {
            if (r < 2 || act2) {
                int row = srowv[r];
                int dst = (r * 256 + t) * 16;
                gload16(Ab + (size_t)(m0 + row) * 512 + gofs + schv[r], &Alds[bf][dst]);
                gload16(Bp8 + (size_t)(n0 + row) * 512 + gofs + schv[r], &Blds[bf][dst]);
            }
        }
    };

    auto COMPUTE = [&](int bf) {
        l64x2 av[4], bp[4];
        #pragma unroll
        for (int i = 0; i < 4; ++i)
            av[i] = *(const l64x2*)&Alds[bf][(wm * 64 + i * 16 + li) * 80 + g * 16];
        #pragma unroll
        for (int j = 0; j < 4; ++j)
            bp[j] = *(const l64x2*)&Blds[bf][(wn * 64 + j * 16 + li) * 80 + g * 16];
        #pragma unroll
        for (int h = 0; h < 2; ++h)
            #pragma unroll
            for (int i = 0; i < 4; ++i)
                #pragma unroll
                for (int j = 0; j < 4; ++j)
                    acc[i][j] = __builtin_amdgcn_mfma_f32_16x16x32_fp8_fp8(
                        av[i][h], bp[j][h], acc[i][j], 0, 0, 0);
    };

    STAGE(0, 0);
    __syncthreads();
    int bf = 0;
    for (int kc2 = 0; kc2 < 8; ++kc2) {
        if (kc2 + 1 < 8) STAGE(bf ^ 1, kc2 + 1);
        COMPUTE(bf);
        __syncthreads();
        bf ^= 1;
    }

    const float SCL = 0.015625f;   // 1/64
    #pragma unroll
    for (int fm = 0; fm < 4; ++fm) {
        #pragma unroll
        for (int fn = 0; fn < 4; ++fn) {
            int mrow = m0 + wm * 64 + fm * 16 + g * 4;
            int ncol = n0 + wn * 64 + fn * 16 + li;
            size_t dst = ((size_t)b * C_DIM + ncol) * HW + mrow;
            float bb = bias[ncol];
            float4 xr = *(const float4*)(resid + dst);
            float4 o;
            o.x = acc[fm][fn][0] * SCL + bb + xr.x;
            o.y = acc[fm][fn][1] * SCL + bb + xr.y;
            o.z = acc[fm][fn][2] * SCL + bb + xr.z;
            o.w = acc[fm][fn][3] * SCL + bb + xr.w;
            *(float4*)(Out + dst) = o;
        }
    }
}

// ---------------- flash attention (r8, frozen): fp8 QK path ----------------
#define KT 32
#define NTILES 64
__global__ __launch_bounds__(512, 2) void k_attn(
        const short* __restrict__ qT, const unsigned char* __restrict__ kT8,
        const short* __restrict__ vg, short* __restrict__ O0,
        short* __restrict__ O1, float* __restrict__ L0, float* __restrict__ L1)
{
    __shared__ __align__(16) short pool[73728];
    unsigned char* Kp8 = (unsigned char*)pool;
    short* Vp = pool + 16384;
    short* Pp = pool + 57344;

    int bid0 = blockIdx.x;
    int bid = (bid0 & 7) * 32 + (bid0 >> 3);
    int qt = bid & 31, ks = (bid >> 5) & 1, b = bid >> 6;
    int m0 = qt * 128;
    int t = threadIdx.x, lane = t & 63, w = t >> 6;
    int g = lane >> 4, li = lane & 15;
    int l31 = lane & 31, l5 = lane >> 5;

    const unsigned char* kb8 = kT8 + ((size_t)b * HW + (size_t)ks * 2048) * 512;
    const short* vb = vg + (size_t)b * C_DIM * HW + ks * 2048;

    long long qf8[16];
    {
        const short* qrow = qT + ((size_t)b * HW + m0 + w * 16 + li) * C_DIM;
        #pragma unroll
        for (int kc = 0; kc < 16; ++kc) {
            bf16x8 qv = *(const bf16x8*)&qrow[kc * 32 + g * 8];
            int lo = __builtin_amdgcn_cvt_pk_fp8_f32(b2f(qv[0]), b2f(qv[1]), 0, false);
            lo     = __builtin_amdgcn_cvt_pk_fp8_f32(b2f(qv[2]), b2f(qv[3]), lo, true);
            int hi = __builtin_amdgcn_cvt_pk_fp8_f32(b2f(qv[4]), b2f(qv[5]), 0, false);
            hi     = __builtin_amdgcn_cvt_pk_fp8_f32(b2f(qv[6]), b2f(qv[7]), hi, true);
            qf8[kc] = ((long long)(unsigned)hi << 32) | (unsigned)lo;
        }
    }
    f32x16 oacc[8];
    #pragma unroll
    for (int a = 0; a < 8; ++a) oacc[a] = zero16();
    float lsum = 0.f;

    const unsigned char* ksrc8 = kb8 + (size_t)(t & 31) * 512 + (t >> 5) * 16;
    int voff[5];
    #pragma unroll
    for (int r = 0; r < 5; ++r) {
        int D = r * 512 + t;
        int ch = D / 5;
        int c  = D - ch * 5;
        voff[r] = (c < 4) ? ch * 4096 + c * 8 : 0;
    }

    const float SC = 0.044194173824159216f * 1.4426950408889634f;

    auto STAGE = [&](int buf, int nt) {
        int n0 = nt * KT;
        const unsigned char* kS = ksrc8 + (size_t)n0 * 512;
        unsigned char* kD = Kp8 + buf * 16384 + t * 16;
        gload16(kS, kD);
        gload16(kS + 256, kD + 8192);
        short* vD = Vp + buf * 20480 + t * 8;
        #pragma unroll
        for (int r = 0; r < 5; ++r)
            gload16(vb + voff[r] + n0, vD + r * 4096);
    };

    STAGE(0, 0);
    asm volatile("s_waitcnt vmcnt(0)" ::: "memory");
    __builtin_amdgcn_s_barrier();
    __builtin_amdgcn_sched_barrier(0);

    int buf = 0;
    for (int nt = 0; nt < NTILES; ++nt) {
        if (nt + 1 < NTILES) STAGE(buf ^ 1, nt + 1);

        const unsigned char* kbase8 = Kp8 + buf * 16384 + g * 512 + li * 16;
        f32x4 s0[2], s1[2];
        s0[0] = zero4(); s0[1] = zero4(); s1[0] = zero4(); s1[1] = zero4();
        __builtin_amdgcn_s_setprio(1);
        #pragma unroll
        for (int kcp = 0; kcp < 8; ++kcp) {
            #pragma unroll
            for (int fn = 0; fn < 2; ++fn) {
                l64x2 kv = *(const l64x2*)&kbase8[kcp * 2048 + fn * 256];
                s0[fn] = __builtin_amdgcn_mfma_f32_16x16x32_fp8_fp8(kv[0], qf8[2 * kcp],     s0[fn], 0, 0, 0);
                s1[fn] = __builtin_amdgcn_mfma_f32_16x16x32_fp8_fp8(kv[1], qf8[2 * kcp + 1], s1[fn], 0, 0, 0);
            }
        }
        __builtin_amdgcn_s_setprio(0);
        #pragma unroll
        for (int fn = 0; fn < 2; ++fn) {
            float e0 = exp2f((s0[fn][0] + s1[fn][0]) * SC);
            float e1 = exp2f((s0[fn][1] + s1[fn][1]) * SC);
            float e2 = exp2f((s0[fn][2] + s1[fn][2]) * SC);
            float e3 = exp2f((s0[fn][3] + s1[fn][3]) * SC);
            lsum += (e0 + e1) + (e2 + e3);
            union { __hip_bfloat162 h; unsigned u; } p01, p23;
            p01.h = __float22bfloat162_rn(make_float2(e0, e1));
            p23.h = __float22bfloat162_rn(make_float2(e2, e3));
            *(uint2*)&Pp[(w * 16 + li) * 40 + fn * 16 + g * 4] = make_uint2(p01.u, p23.u);
        }

        asm volatile("s_waitcnt lgkmcnt(0)" ::: "memory");
        __builtin_amdgcn_s_barrier();
        __builtin_amdgcn_sched_barrier(0);

        const short* vbase = Vp + buf * 20480 + (size_t)w * 64 * 40;
        bf16x8 vf[2][2];
        #pragma unroll
        for (int cht = 0; cht < 2; ++cht)
            #pragma unroll
            for (int kx = 0; kx < 2; ++kx)
                vf[cht][kx] = *(const bf16x8*)&vbase[(cht * 32 + l31) * 40 + kx * 16 + l5 * 8];
        __builtin_amdgcn_s_setprio(1);
        #pragma unroll
        for (int q2 = 0; q2 < 4; ++q2) {
            #pragma unroll
            for (int kx = 0; kx < 2; ++kx) {
                bf16x8 pf = *(const bf16x8*)&Pp[(q2 * 32 + l31) * 40 + kx * 16 + l5 * 8];
                oacc[q2 * 2 + 0] = __builtin_amdgcn_mfma_f32_32x32x16_bf16(vf[0][kx], pf, oacc[q2 * 2 + 0], 0, 0, 0);
                oacc[q2 * 2 + 1] = __builtin_amdgcn_mfma_f32_32x32x16_bf16(vf[1][kx], pf, oacc[q2 * 2 + 1], 0, 0, 0);
            }
        }
        __builtin_amdgcn_s_setprio(0);

        asm volatile("s_waitcnt vmcnt(0)" ::: "memory");
        __builtin_amdgcn_s_barrier();
        __builtin_amdgcn_sched_barrier(0);
        buf ^= 1;
    }

    lsum += __shfl_xor(lsum, 16);
    lsum += __shfl_xor(lsum, 32);
    float* Lb = (ks ? L1 : L0) + (size_t)b * HW + m0 + w * 16;
    if (lane < 16) Lb[lane] = lsum;

    short* tp = pool + w * 9216;
    #pragma unroll
    for (int a = 0; a < 8; ++a) {
        int q2 = a >> 1, cht = a & 1;
        int q_l = q2 * 32 + l31;
        #pragma unroll
        for (int rq = 0; rq < 4; ++rq) {
            int chb = cht * 32 + rq * 8 + l5 * 4;
            union { __hip_bfloat162 h; unsigned u; } x01, x23;
            x01.h = __float22bfloat162_rn(make_float2(oacc[a][rq * 4 + 0], oacc[a][rq * 4 + 1]));
            x23.h = __float22bfloat162_rn(make_float2(oacc[a][rq * 4 + 2], oacc[a][rq * 4 + 3]));
            *(uint2*)&tp[q_l * 72 + chb] = make_uint2(x01.u, x23.u);
        }
    }
    asm volatile("s_waitcnt lgkmcnt(0)" ::: "memory");
    __builtin_amdgcn_sched_barrier(0);
    short* Ob = (ks ? O1 : O0) + ((size_t)b * HW + m0) * C_DIM + w * 64;
    #pragma unroll
    for (int qg = 0; qg < 16; ++qg) {
        int qr = qg * 8 + (lane >> 3);
        bf16x8 v = *(const bf16x8*)&tp[qr * 72 + (lane & 7) * 8];
        *(bf16x8*)&Ob[(size_t)qr * C_DIM + (lane & 7) * 8] = v;
    }
}

// combine -> packed fp8 oatt8: thread's 8 consecutive channels = 8 consecutive
// packed bytes (group ct=cidx>>3, g=cidx&3, half=(cidx>>2)&1) -> one uint2.
__global__ void k_att_comb(const short* __restrict__ O0, const short* __restrict__ O1,
                           const float* __restrict__ L0, const float* __restrict__ L1,
                           unsigned char* __restrict__ oatt8) {
    int i = blockIdx.x * 256 + threadIdx.x;
    int row = i >> 6;
    int cidx = i & 63;
    int c0 = cidx * 8;
    float r = 1.0f / (L0[row] + L1[row]);
    size_t base = (size_t)row * C_DIM + c0;
    bf16x8 a = *(const bf16x8*)&O0[base];
    bf16x8 c = *(const bf16x8*)&O1[base];
    float f[8];
    #pragma unroll
    for (int j = 0; j < 8; ++j)
        f[j] = (b2f(a[j]) + b2f(c[j])) * r;
    int lo = __builtin_amdgcn_cvt_pk_fp8_f32(f[0], f[1], 0, false);
    lo     = __builtin_amdgcn_cvt_pk_fp8_f32(f[2], f[3], lo, true);
    int hi = __builtin_amdgcn_cvt_pk_fp8_f32(f[4], f[5], 0, false);
    hi     = __builtin_amdgcn_cvt_pk_fp8_f32(f[6], f[7], hi, true);
    int pbyte = (cidx >> 3) * 64 + (cidx & 3) * 16 + ((cidx >> 2) & 1) * 8;
    *(uint2*)&oatt8[(size_t)row * 512 + pbyte] = make_uint2((unsigned)lo, (unsigned)hi);
}

// ---------------- launch ----------------
extern "C" void kernel_launch(void* const* d_in, const int* in_sizes, int n_in,
                              void* d_out, int out_size, void* d_ws, size_t ws_size,
                              hipStream_t stream) {
    const float* x    = (const float*)d_in[0];
    const float* ln_w = (const float*)d_in[1];
    const float* ln_b = (const float*)d_in[2];
    const float* wq   = (const float*)d_in[3];
    const float* wk   = (const float*)d_in[4];
    const float* wv   = (const float*)d_in[5];
    const float* wp   = (const float*)d_in[6];
    const float* bp   = (const float*)d_in[7];
    float* out = (float*)d_out;

    char* ws = (char*)d_ws;
    size_t off = 0;
    auto alloc = [&](size_t bytes) {
        char* p = ws + off;
        off += (bytes + 255) & ~(size_t)255;
        return p;
    };
    short* hp   = (short*)alloc((size_t)BATCH * PPIX * C_DIM * 2);   // O-partial 0 scratch
    unsigned char* hp8 = (unsigned char*)alloc((size_t)BATCH * PPIX * 512);  // LN out; later kT8
    unsigned char* wq8 = (unsigned char*)alloc((size_t)512 * 512);
    unsigned char* wk8 = (unsigned char*)alloc((size_t)512 * 4608);
    unsigned char* wv8 = (unsigned char*)alloc((size_t)512 * 4608);
    unsigned char* wp8 = (unsigned char*)alloc((size_t)512 * 512);
    short* qT   = (short*)alloc((size_t)BATCH * HW * C_DIM * 2);
    short* kT   = (short*)alloc((size_t)BATCH * HW * C_DIM * 2);     // later oatt8
    short* vg   = (short*)alloc((size_t)BATCH * HW * C_DIM * 2);
    short* oatt = (short*)alloc((size_t)BATCH * HW * C_DIM * 2);     // O-partial 1
    float* mean = (float*)alloc((size_t)BATCH * HW * 4);             // Lsum 0
    float* rstd = (float*)alloc((size_t)BATCH * HW * 4);             // Lsum 1

    hipMemsetAsync(hp8, 0, (size_t)BATCH * PPIX * 512, stream);
    k_reorder_w18<<<128, 256, 0, stream>>>(wq, wq8);
    k_reorder_w18<<<128, 256, 0, stream>>>(wp, wp8);
    k_reorder_w38<<<1152, 256, 0, stream>>>(wk, wk8);
    k_reorder_w38<<<1152, 256, 0, stream>>>(wv, wv8);
    k_ln_fused<<<256, 256, 0, stream>>>(x, ln_w, ln_b, hp8);

    k_gemm_q8<<<512, 256, 0, stream>>>(hp8, wq8, qT);
    k_gemm_kv8<<<512, 256, 0, stream>>>(hp8, wk8, wv8, kT, vg);

    // hp8 dead -> reuse as the 8MB packed fp8 K buffer
    unsigned char* kT8 = hp8;
    k_cvt_k8<<<4096, 256, 0, stream>>>(kT, kT8);

    short* Op0 = hp;
    short* Op1 = oatt;
    float* Ls0 = mean;
    float* Ls1 = rstd;
    k_attn<<<256, 512, 0, stream>>>(qT, kT8, vg, Op0, Op1, Ls0, Ls1);

    // kT dead after cvt_k8 -> reuse as packed fp8 attention output
    unsigned char* oatt8 = (unsigned char*)kT;
    k_att_comb<<<4096, 256, 0, stream>>>(Op0, Op1, Ls0, Ls1, oatt8);

    k_gemm_p8<<<512, 256, 0, stream>>>(oatt8, wp8, out, bp, x);
}

// Round 21
// 318.296 us; speedup vs baseline: 4.2078x; 1.0172x over previous
//
#include <hip/hip_runtime.h>
#include <hip/hip_bf16.h>

#define C_DIM 512
#define HW    4096
#define BATCH 4
#define PW    66
#define PPIX  (PW*PW)   // 4356

typedef __attribute__((ext_vector_type(8))) short bf16x8;
typedef __attribute__((ext_vector_type(4))) float f32x4;
typedef __attribute__((ext_vector_type(16))) float f32x16;
typedef __attribute__((ext_vector_type(2))) long long l64x2;

static __device__ __forceinline__ short f2b(float f) {
    union { float f; unsigned u; } v; v.f = f;
    unsigned r = v.u + 0x7fffu + ((v.u >> 16) & 1u);
    return (short)(r >> 16);
}
static __device__ __forceinline__ float b2f(short s) {
    union { unsigned u; float f; } v; v.u = ((unsigned)(unsigned short)s) << 16;
    return v.f;
}

static __device__ __forceinline__ f32x4 zero4() {
    f32x4 v = {0.f, 0.f, 0.f, 0.f};
    return v;
}
static __device__ __forceinline__ f32x16 zero16() {
    f32x16 v = {0.f,0.f,0.f,0.f, 0.f,0.f,0.f,0.f, 0.f,0.f,0.f,0.f, 0.f,0.f,0.f,0.f};
    return v;
}

static __device__ __forceinline__ void gload16(const void* g, void* l) {
    __builtin_amdgcn_global_load_lds(
        (__attribute__((address_space(1))) void*)g,
        (__attribute__((address_space(3))) void*)l, 16, 0, 0);
}

static __device__ __forceinline__ unsigned char f2fp8(float f) {
    int pk = __builtin_amdgcn_cvt_pk_fp8_f32(f, f, 0, false);
    return (unsigned char)(pk & 0xff);
}

// ---------------- weight prep ----------------
// 3x3 weights float -> fp8 e4m3 x64, packed rows of 4608 bytes (see r13)
__global__ void k_reorder_w38(const float* __restrict__ w, unsigned char* __restrict__ out) {
    int i = blockIdx.x * 256 + threadIdx.x;
    int o = i / 576;
    int p8 = (i - o * 576) * 8;
    int kc2 = p8 >> 6;
    int tap = kc2 >> 3;
    int p = p8 & 63;
    int g = (p >> 4) & 3, half = (p >> 3) & 1;
    int c0 = (kc2 & 7) * 64 + half * 32 + g * 8;
    const float* src = w + ((size_t)o * 512 + c0) * 9 + tap;
    float f0 = src[0] * 64.f, f1 = src[9] * 64.f, f2 = src[18] * 64.f, f3 = src[27] * 64.f;
    float f4 = src[36] * 64.f, f5 = src[45] * 64.f, f6 = src[54] * 64.f, f7 = src[63] * 64.f;
    int lo = __builtin_amdgcn_cvt_pk_fp8_f32(f0, f1, 0, false);
    lo     = __builtin_amdgcn_cvt_pk_fp8_f32(f2, f3, lo, true);
    int hi = __builtin_amdgcn_cvt_pk_fp8_f32(f4, f5, 0, false);
    hi     = __builtin_amdgcn_cvt_pk_fp8_f32(f6, f7, hi, true);
    *(uint2*)&out[(size_t)o * 4608 + p8] = make_uint2((unsigned)lo, (unsigned)hi);
}

// 1x1 weights float -> fp8 e4m3 x64, packed rows of 512 bytes (verified r14/r16)
__global__ void k_reorder_w18(const float* __restrict__ w, unsigned char* __restrict__ out) {
    int i = blockIdx.x * 256 + threadIdx.x;    // 32768 threads, 8 bytes each
    int o = i >> 6;
    int p8 = (i & 63) * 8;
    int grp = p8 >> 6;
    int p = p8 & 63;
    int g = (p >> 4) & 3, half = (p >> 3) & 1;
    int c0 = grp * 64 + half * 32 + g * 8;
    const float* src = w + (size_t)o * 512 + c0;
    int lo = __builtin_amdgcn_cvt_pk_fp8_f32(src[0] * 64.f, src[1] * 64.f, 0, false);
    lo     = __builtin_amdgcn_cvt_pk_fp8_f32(src[2] * 64.f, src[3] * 64.f, lo, true);
    int hi = __builtin_amdgcn_cvt_pk_fp8_f32(src[4] * 64.f, src[5] * 64.f, 0, false);
    hi     = __builtin_amdgcn_cvt_pk_fp8_f32(src[6] * 64.f, src[7] * 64.f, hi, true);
    *(uint2*)&out[(size_t)o * 512 + p8] = make_uint2((unsigned)lo, (unsigned)hi);
}

// ---------------- fused layernorm -> packed fp8 hp8 ----------------
__global__ void k_ln_fused(const float* __restrict__ x, const float* __restrict__ lnw,
                           const float* __restrict__ lnb, unsigned char* __restrict__ hp8) {
    __shared__ float red[8][64];
    __shared__ float mean_s[64], rstd_s[64];
    __shared__ short tile[64][65];
    int bid = blockIdx.x;
    int y = bid & 63, b = bid >> 6;
    int t = threadIdx.x;
    int px = t & 63, cg = t >> 6;
    const float* xb = x + (size_t)b * C_DIM * HW + (size_t)y * 64;

    float s = 0.f, sq = 0.f;
    for (int c = cg * 128; c < cg * 128 + 128; ++c) {
        float v = xb[(size_t)c * HW + px];
        s += v; sq += v * v;
    }
    red[cg][px] = s;
    red[4 + cg][px] = sq;
    __syncthreads();
    if (t < 64) {
        float S = red[0][t] + red[1][t] + red[2][t] + red[3][t];
        float Q = red[4][t] + red[5][t] + red[6][t] + red[7][t];
        float mu  = S * (1.0f / C_DIM);
        float var = Q * (1.0f / C_DIM) - mu * mu;
        mean_s[t] = mu;
        rstd_s[t] = 1.0f / sqrtf(var + 1e-6f);
    }
    __syncthreads();
    float mu = mean_s[px], rs = rstd_s[px];
    int chn = t & 7, pxe = t >> 3;
    int clocal = (chn & 1) * 32 + ((chn >> 1) & 3) * 8;
    for (int ct = 0; ct < 8; ++ct) {
        int c0 = ct * 64;
        #pragma unroll
        for (int cc = 0; cc < 64; cc += 4) {
            int c = c0 + cc + cg;
            float v = xb[(size_t)c * HW + px];
            tile[cc + cg][px] = f2b((v - mu) * rs * lnw[c] + lnb[c]);
        }
        __syncthreads();
        #pragma unroll
        for (int h = 0; h < 2; ++h) {
            int pix = pxe + h * 32;
            float f0 = b2f(tile[clocal + 0][pix]);
            float f1 = b2f(tile[clocal + 1][pix]);
            float f2 = b2f(tile[clocal + 2][pix]);
            float f3 = b2f(tile[clocal + 3][pix]);
            float f4 = b2f(tile[clocal + 4][pix]);
            float f5 = b2f(tile[clocal + 5][pix]);
            float f6 = b2f(tile[clocal + 6][pix]);
            float f7 = b2f(tile[clocal + 7][pix]);
            int lo = __builtin_amdgcn_cvt_pk_fp8_f32(f0, f1, 0, false);
            lo     = __builtin_amdgcn_cvt_pk_fp8_f32(f2, f3, lo, true);
            int hi = __builtin_amdgcn_cvt_pk_fp8_f32(f4, f5, 0, false);
            hi     = __builtin_amdgcn_cvt_pk_fp8_f32(f6, f7, hi, true);
            size_t row = (size_t)b * PPIX + (size_t)(y + 1) * PW + 1 + pix;
            *(uint2*)&hp8[row * 512 + c0 + chn * 8] = make_uint2((unsigned)lo, (unsigned)hi);
        }
        __syncthreads();
    }
}

// ---------------- fused K+V 3x3 conv, fp8; K emitted directly as packed fp8 ----
// K byte position for channel c (inverse of the r8 cvt_k8 map, which attention's
// QK fragment reads consume): pbyte = (c>>6)*64 + ((c>>3)&3)*16 + ((c>>5)&1)*8 + (c&7).
__global__ __launch_bounds__(256, 2) void k_gemm_kv8(
        const unsigned char* __restrict__ A8, const unsigned char* __restrict__ Bk8,
        const unsigned char* __restrict__ Bv8, unsigned char* __restrict__ OutK8,
        short* __restrict__ OutV)
{
    __shared__ unsigned char Alds[2][10240];    // 128 rows x 80 B
    __shared__ unsigned char Bklds[2][10240];
    __shared__ unsigned char Bvlds[2][10240];
    int bid = blockIdx.x;
    int mt = bid & 31, nt = (bid >> 5) & 3, b = bid >> 7;
    int m0 = mt * 128, n0 = nt * 128;
    int t = threadIdx.x;
    int lane = t & 63, w = t >> 6;
    int wm = w >> 1, wn = w & 1;
    int g = lane >> 4, li = lane & 15;
    const unsigned char* Ab = A8 + (size_t)b * PPIX * 512;

    int srowv[3], schv[3];
    #pragma unroll
    for (int r = 0; r < 3; ++r) {
        int slot = r * 256 + t;
        int row = slot / 5;
        int ch = slot - row * 5;
        srowv[r] = row;
        schv[r] = (ch < 4) ? ch * 16 : 0;     // byte offset; pad loads dummy 16B
    }
    bool act2 = (w < 2);

    f32x4 accK[4][4], accV[4][4];
    #pragma unroll
    for (int i = 0; i < 4; ++i)
        #pragma unroll
        for (int j = 0; j < 4; ++j) { accK[i][j] = zero4(); accV[i][j] = zero4(); }

    auto STAGE = [&](int bf, int kc2) {
        int tap = kc2 >> 3;
        int gofs = (kc2 & 7) * 64;
        int ty3 = tap / 3, tx3 = tap % 3;
        #pragma unroll
        for (int r = 0; r < 3; ++r) {
            if (r < 2 || act2) {
                int row = srowv[r];
                int m = m0 + row;
                int yy = m >> 6, xx = m & 63;
                int pp = (yy + ty3) * PW + xx + tx3;
                int dst = (r * 256 + t) * 16;
                gload16(Ab + (size_t)pp * 512 + gofs + schv[r], &Alds[bf][dst]);
                size_t gb = (size_t)(n0 + row) * 4608 + kc2 * 64 + schv[r];
                gload16(Bk8 + gb, &Bklds[bf][dst]);
                gload16(Bv8 + gb, &Bvlds[bf][dst]);
            }
        }
    };

    auto COMPUTE = [&](int bf) {
        l64x2 av[4], bk[4], bv[4];
        #pragma unroll
        for (int i = 0; i < 4; ++i)
            av[i] = *(const l64x2*)&Alds[bf][(wm * 64 + i * 16 + li) * 80 + g * 16];
        #pragma unroll
        for (int j = 0; j < 4; ++j)
            bk[j] = *(const l64x2*)&Bklds[bf][(wn * 64 + j * 16 + li) * 80 + g * 16];
        #pragma unroll
        for (int j = 0; j < 4; ++j)
            bv[j] = *(const l64x2*)&Bvlds[bf][(wn * 64 + j * 16 + li) * 80 + g * 16];
        #pragma unroll
        for (int h = 0; h < 2; ++h) {
            #pragma unroll
            for (int i = 0; i < 4; ++i)
                #pragma unroll
                for (int j = 0; j < 4; ++j)
                    accK[i][j] = __builtin_amdgcn_mfma_f32_16x16x32_fp8_fp8(
                        av[i][h], bk[j][h], accK[i][j], 0, 0, 0);
            #pragma unroll
            for (int i = 0; i < 4; ++i)
                #pragma unroll
                for (int j = 0; j < 4; ++j)
                    accV[i][j] = __builtin_amdgcn_mfma_f32_16x16x32_fp8_fp8(
                        av[i][h], bv[j][h], accV[i][j], 0, 0, 0);
        }
    };

    STAGE(0, 0);
    __syncthreads();
    int bf = 0;
    for (int kc2 = 0; kc2 < 72; ++kc2) {
        if (kc2 + 1 < 72) STAGE(bf ^ 1, kc2 + 1);
        COMPUTE(bf);
        __syncthreads();
        bf ^= 1;
    }

    const float SCL = 0.015625f;   // 1/64 (weights were pre-scaled x64)
    #pragma unroll
    for (int fm = 0; fm < 4; ++fm) {
        #pragma unroll
        for (int fn = 0; fn < 4; ++fn) {
            int mrow = m0 + wm * 64 + fm * 16 + g * 4;
            int ncol = n0 + wn * 64 + fn * 16 + li;
            // K -> packed fp8 byte at pbyte(ncol), rows mrow..mrow+3
            int pbyte = (ncol >> 6) * 64 + ((ncol >> 3) & 3) * 16
                      + ((ncol >> 5) & 1) * 8 + (ncol & 7);
            #pragma unroll
            for (int i = 0; i < 4; ++i) {
                size_t dst = ((size_t)b * HW + mrow + i) * 512 + pbyte;
                OutK8[dst] = f2fp8(accK[fm][fn][i] * SCL);
            }
            size_t dstv = ((size_t)b * C_DIM + ncol) * HW + mrow;
            short4 sv = make_short4(f2b(accV[fm][fn][0] * SCL), f2b(accV[fm][fn][1] * SCL),
                                    f2b(accV[fm][fn][2] * SCL), f2b(accV[fm][fn][3] * SCL));
            *(short4*)(OutV + dstv) = sv;
        }
    }
}

// ---------------- q 1x1 conv, fp8 (r16, verified) ----------------
__global__ __launch_bounds__(256, 2) void k_gemm_q8(
        const unsigned char* __restrict__ A8, const unsigned char* __restrict__ Bq8,
        short* __restrict__ OutQ)
{
    __shared__ unsigned char Alds[2][10240];
    __shared__ unsigned char Blds[2][10240];
    int bid = blockIdx.x;
    int mt = bid & 31, nt = (bid >> 5) & 3, b = bid >> 7;
    int m0 = mt * 128, n0 = nt * 128;
    int t = threadIdx.x;
    int lane = t & 63, w = t >> 6;
    int wm = w >> 1, wn = w & 1;
    int g = lane >> 4, li = lane & 15;
    const unsigned char* Ab = A8 + (size_t)b * PPIX * 512;

    int srowv[3], schv[3];
    #pragma unroll
    for (int r = 0; r < 3; ++r) {
        int slot = r * 256 + t;
        int row = slot / 5;
        int ch = slot - row * 5;
        srowv[r] = row;
        schv[r] = (ch < 4) ? ch * 16 : 0;
    }
    bool act2 = (w < 2);

    f32x4 accQ[4][4];
    #pragma unroll
    for (int i = 0; i < 4; ++i)
        #pragma unroll
        for (int j = 0; j < 4; ++j) accQ[i][j] = zero4();

    auto STAGE = [&](int bf, int kc2) {
        int gofs = kc2 * 64;
        #pragma unroll
        for (int r = 0; r < 3; ++r) {
            if (r < 2 || act2) {
                int row = srowv[r];
                int m = m0 + row;
                int yy = m >> 6, xx = m & 63;
                int pp = (yy + 1) * PW + xx + 1;     // center tap (1x1 conv)
                int dst = (r * 256 + t) * 16;
                gload16(Ab + (size_t)pp * 512 + gofs + schv[r], &Alds[bf][dst]);
                gload16(Bq8 + (size_t)(n0 + row) * 512 + gofs + schv[r], &Blds[bf][dst]);
            }
        }
    };

    auto COMPUTE = [&](int bf) {
        l64x2 av[4], bq[4];
        #pragma unroll
        for (int i = 0; i < 4; ++i)
            av[i] = *(const l64x2*)&Alds[bf][(wm * 64 + i * 16 + li) * 80 + g * 16];
        #pragma unroll
        for (int j = 0; j < 4; ++j)
            bq[j] = *(const l64x2*)&Blds[bf][(wn * 64 + j * 16 + li) * 80 + g * 16];
        #pragma unroll
        for (int h = 0; h < 2; ++h)
            #pragma unroll
            for (int i = 0; i < 4; ++i)
                #pragma unroll
                for (int j = 0; j < 4; ++j)
                    accQ[i][j] = __builtin_amdgcn_mfma_f32_16x16x32_fp8_fp8(
                        av[i][h], bq[j][h], accQ[i][j], 0, 0, 0);
    };

    STAGE(0, 0);
    __syncthreads();
    int bf = 0;
    for (int kc2 = 0; kc2 < 8; ++kc2) {
        if (kc2 + 1 < 8) STAGE(bf ^ 1, kc2 + 1);
        COMPUTE(bf);
        __syncthreads();
        bf ^= 1;
    }

    const float SCL = 0.015625f;   // 1/64
    #pragma unroll
    for (int fm = 0; fm < 4; ++fm) {
        #pragma unroll
        for (int fn = 0; fn < 4; ++fn) {
            int mrow = m0 + wm * 64 + fm * 16 + g * 4;
            int ncol = n0 + wn * 64 + fn * 16 + li;
            #pragma unroll
            for (int i = 0; i < 4; ++i) {
                size_t dst = ((size_t)b * HW + mrow + i) * C_DIM + ncol;
                OutQ[dst] = f2b(accQ[fm][fn][i] * SCL);
            }
        }
    }
}

// ---------------- proj 1x1 conv, fp8 (r17, verified) ----------------
__global__ __launch_bounds__(256, 2) void k_gemm_p8(
        const unsigned char* __restrict__ A8, const unsigned char* __restrict__ Bp8,
        float* __restrict__ Out, const float* __restrict__ bias,
        const float* __restrict__ resid)
{
    __shared__ unsigned char Alds[2][10240];
    __shared__ unsigned char Blds[2][10240];
    int bid = blockIdx.x;
    int mt = bid & 31, nt = (bid >> 5) & 3, b = bid >> 7;
    int m0 = mt * 128, n0 = nt * 128;
    int t = threadIdx.x;
    int lane = t & 63, w = t >> 6;
    int wm = w >> 1, wn = w & 1;
    int g = lane >> 4, li = lane & 15;
    const unsigned char* Ab = A8 + (size_t)b * HW * 512;

    int srowv[3], schv[3];
    #pragma unroll
    for (int r = 0; r < 3; ++r) {
        int slot = r * 256 + t;
        int row = slot / 5;
        int ch = slot - row * 5;
        srowv[r] = row;
        schv[r] = (ch < 4) ? ch * 16 : 0;
    }
    bool act2 = (w < 2);

    f32x4 acc[4][4];
    #pragma unroll
    for (int i = 0; i < 4; ++i)
        #pragma unroll
        for (int j = 0; j < 4; ++j) acc[i][j] = zero4();

    auto STAGE = [&](int bf, int kc2) {
        int gofs = kc2 * 64;
        #pragma unroll
        for (int r = 0; r < 3; ++r) {
            if (r < 2 || act2) {
                int row = srowv[r];
                int dst = (r * 256 + t) * 16;
                gload16(Ab + (size_t)(m0 + row) * 512 + gofs + schv[r], &Alds[bf][dst]);
                gload16(Bp8 + (size_t)(n0 + row) * 512 + gofs + schv[r], &Blds[bf][dst]);
            }
        }
    };

    auto COMPUTE = [&](int bf) {
        l64x2 av[4], bp[4];
        #pragma unroll
        for (int i = 0; i < 4; ++i)
            av[i] = *(const l64x2*)&Alds[bf][(wm * 64 + i * 16 + li) * 80 + g * 16];
        #pragma unroll
        for (int j = 0; j < 4; ++j)
            bp[j] = *(const l64x2*)&Blds[bf][(wn * 64 + j * 16 + li) * 80 + g * 16];
        #pragma unroll
        for (int h = 0; h < 2; ++h)
            #pragma unroll
            for (int i = 0; i < 4; ++i)
                #pragma unroll
                for (int j = 0; j < 4; ++j)
                    acc[i][j] = __builtin_amdgcn_mfma_f32_16x16x32_fp8_fp8(
                        av[i][h], bp[j][h], acc[i][j], 0, 0, 0);
    };

    STAGE(0, 0);
    __syncthreads();
    int bf = 0;
    for (int kc2 = 0; kc2 < 8; ++kc2) {
        if (kc2 + 1 < 8) STAGE(bf ^ 1, kc2 + 1);
        COMPUTE(bf);
        __syncthreads();
        bf ^= 1;
    }

    const float SCL = 0.015625f;   // 1/64
    #pragma unroll
    for (int fm = 0; fm < 4; ++fm) {
        #pragma unroll
        for (int fn = 0; fn < 4; ++fn) {
            int mrow = m0 + wm * 64 + fm * 16 + g * 4;
            int ncol = n0 + wn * 64 + fn * 16 + li;
            size_t dst = ((size_t)b * C_DIM + ncol) * HW + mrow;
            float bb = bias[ncol];
            float4 xr = *(const float4*)(resid + dst);
            float4 o;
            o.x = acc[fm][fn][0] * SCL + bb + xr.x;
            o.y = acc[fm][fn][1] * SCL + bb + xr.y;
            o.z = acc[fm][fn][2] * SCL + bb + xr.z;
            o.w = acc[fm][fn][3] * SCL + bb + xr.w;
            *(float4*)(Out + dst) = o;
        }
    }
}

// ---------------- flash attention (r8, frozen): fp8 QK path ----------------
#define KT 32
#define NTILES 64
__global__ __launch_bounds__(512, 2) void k_attn(
        const short* __restrict__ qT, const unsigned char* __restrict__ kT8,
        const short* __restrict__ vg, short* __restrict__ O0,
        short* __restrict__ O1, float* __restrict__ L0, float* __restrict__ L1)
{
    __shared__ __align__(16) short pool[73728];
    unsigned char* Kp8 = (unsigned char*)pool;
    short* Vp = pool + 16384;
    short* Pp = pool + 57344;

    int bid0 = blockIdx.x;
    int bid = (bid0 & 7) * 32 + (bid0 >> 3);
    int qt = bid & 31, ks = (bid >> 5) & 1, b = bid >> 6;
    int m0 = qt * 128;
    int t = threadIdx.x, lane = t & 63, w = t >> 6;
    int g = lane >> 4, li = lane & 15;
    int l31 = lane & 31, l5 = lane >> 5;

    const unsigned char* kb8 = kT8 + ((size_t)b * HW + (size_t)ks * 2048) * 512;
    const short* vb = vg + (size_t)b * C_DIM * HW + ks * 2048;

    long long qf8[16];
    {
        const short* qrow = qT + ((size_t)b * HW + m0 + w * 16 + li) * C_DIM;
        #pragma unroll
        for (int kc = 0; kc < 16; ++kc) {
            bf16x8 qv = *(const bf16x8*)&qrow[kc * 32 + g * 8];
            int lo = __builtin_amdgcn_cvt_pk_fp8_f32(b2f(qv[0]), b2f(qv[1]), 0, false);
            lo     = __builtin_amdgcn_cvt_pk_fp8_f32(b2f(qv[2]), b2f(qv[3]), lo, true);
            int hi = __builtin_amdgcn_cvt_pk_fp8_f32(b2f(qv[4]), b2f(qv[5]), 0, false);
            hi     = __builtin_amdgcn_cvt_pk_fp8_f32(b2f(qv[6]), b2f(qv[7]), hi, true);
            qf8[kc] = ((long long)(unsigned)hi << 32) | (unsigned)lo;
        }
    }
    f32x16 oacc[8];
    #pragma unroll
    for (int a = 0; a < 8; ++a) oacc[a] = zero16();
    float lsum = 0.f;

    const unsigned char* ksrc8 = kb8 + (size_t)(t & 31) * 512 + (t >> 5) * 16;
    int voff[5];
    #pragma unroll
    for (int r = 0; r < 5; ++r) {
        int D = r * 512 + t;
        int ch = D / 5;
        int c  = D - ch * 5;
        voff[r] = (c < 4) ? ch * 4096 + c * 8 : 0;
    }

    const float SC = 0.044194173824159216f * 1.4426950408889634f;

    auto STAGE = [&](int buf, int nt) {
        int n0 = nt * KT;
        const unsigned char* kS = ksrc8 + (size_t)n0 * 512;
        unsigned char* kD = Kp8 + buf * 16384 + t * 16;
        gload16(kS, kD);
        gload16(kS + 256, kD + 8192);
        short* vD = Vp + buf * 20480 + t * 8;
        #pragma unroll
        for (int r = 0; r < 5; ++r)
            gload16(vb + voff[r] + n0, vD + r * 4096);
    };

    STAGE(0, 0);
    asm volatile("s_waitcnt vmcnt(0)" ::: "memory");
    __builtin_amdgcn_s_barrier();
    __builtin_amdgcn_sched_barrier(0);

    int buf = 0;
    for (int nt = 0; nt < NTILES; ++nt) {
        if (nt + 1 < NTILES) STAGE(buf ^ 1, nt + 1);

        const unsigned char* kbase8 = Kp8 + buf * 16384 + g * 512 + li * 16;
        f32x4 s0[2], s1[2];
        s0[0] = zero4(); s0[1] = zero4(); s1[0] = zero4(); s1[1] = zero4();
        __builtin_amdgcn_s_setprio(1);
        #pragma unroll
        for (int kcp = 0; kcp < 8; ++kcp) {
            #pragma unroll
            for (int fn = 0; fn < 2; ++fn) {
                l64x2 kv = *(const l64x2*)&kbase8[kcp * 2048 + fn * 256];
                s0[fn] = __builtin_amdgcn_mfma_f32_16x16x32_fp8_fp8(kv[0], qf8[2 * kcp],     s0[fn], 0, 0, 0);
                s1[fn] = __builtin_amdgcn_mfma_f32_16x16x32_fp8_fp8(kv[1], qf8[2 * kcp + 1], s1[fn], 0, 0, 0);
            }
        }
        __builtin_amdgcn_s_setprio(0);
        #pragma unroll
        for (int fn = 0; fn < 2; ++fn) {
            float e0 = exp2f((s0[fn][0] + s1[fn][0]) * SC);
            float e1 = exp2f((s0[fn][1] + s1[fn][1]) * SC);
            float e2 = exp2f((s0[fn][2] + s1[fn][2]) * SC);
            float e3 = exp2f((s0[fn][3] + s1[fn][3]) * SC);
            lsum += (e0 + e1) + (e2 + e3);
            union { __hip_bfloat162 h; unsigned u; } p01, p23;
            p01.h = __float22bfloat162_rn(make_float2(e0, e1));
            p23.h = __float22bfloat162_rn(make_float2(e2, e3));
            *(uint2*)&Pp[(w * 16 + li) * 40 + fn * 16 + g * 4] = make_uint2(p01.u, p23.u);
        }

        asm volatile("s_waitcnt lgkmcnt(0)" ::: "memory");
        __builtin_amdgcn_s_barrier();
        __builtin_amdgcn_sched_barrier(0);

        const short* vbase = Vp + buf * 20480 + (size_t)w * 64 * 40;
        bf16x8 vf[2][2];
        #pragma unroll
        for (int cht = 0; cht < 2; ++cht)
            #pragma unroll
            for (int kx = 0; kx < 2; ++kx)
                vf[cht][kx] = *(const bf16x8*)&vbase[(cht * 32 + l31) * 40 + kx * 16 + l5 * 8];
        __builtin_amdgcn_s_setprio(1);
        #pragma unroll
        for (int q2 = 0; q2 < 4; ++q2) {
            #pragma unroll
            for (int kx = 0; kx < 2; ++kx) {
                bf16x8 pf = *(const bf16x8*)&Pp[(q2 * 32 + l31) * 40 + kx * 16 + l5 * 8];
                oacc[q2 * 2 + 0] = __builtin_amdgcn_mfma_f32_32x32x16_bf16(vf[0][kx], pf, oacc[q2 * 2 + 0], 0, 0, 0);
                oacc[q2 * 2 + 1] = __builtin_amdgcn_mfma_f32_32x32x16_bf16(vf[1][kx], pf, oacc[q2 * 2 + 1], 0, 0, 0);
            }
        }
        __builtin_amdgcn_s_setprio(0);

        asm volatile("s_waitcnt vmcnt(0)" ::: "memory");
        __builtin_amdgcn_s_barrier();
        __builtin_amdgcn_sched_barrier(0);
        buf ^= 1;
    }

    lsum += __shfl_xor(lsum, 16);
    lsum += __shfl_xor(lsum, 32);
    float* Lb = (ks ? L1 : L0) + (size_t)b * HW + m0 + w * 16;
    if (lane < 16) Lb[lane] = lsum;

    short* tp = pool + w * 9216;
    #pragma unroll
    for (int a = 0; a < 8; ++a) {
        int q2 = a >> 1, cht = a & 1;
        int q_l = q2 * 32 + l31;
        #pragma unroll
        for (int rq = 0; rq < 4; ++rq) {
            int chb = cht * 32 + rq * 8 + l5 * 4;
            union { __hip_bfloat162 h; unsigned u; } x01, x23;
            x01.h = __float22bfloat162_rn(make_float2(oacc[a][rq * 4 + 0], oacc[a][rq * 4 + 1]));
            x23.h = __float22bfloat162_rn(make_float2(oacc[a][rq * 4 + 2], oacc[a][rq * 4 + 3]));
            *(uint2*)&tp[q_l * 72 + chb] = make_uint2(x01.u, x23.u);
        }
    }
    asm volatile("s_waitcnt lgkmcnt(0)" ::: "memory");
    __builtin_amdgcn_sched_barrier(0);
    short* Ob = (ks ? O1 : O0) + ((size_t)b * HW + m0) * C_DIM + w * 64;
    #pragma unroll
    for (int qg = 0; qg < 16; ++qg) {
        int qr = qg * 8 + (lane >> 3);
        bf16x8 v = *(const bf16x8*)&tp[qr * 72 + (lane & 7) * 8];
        *(bf16x8*)&Ob[(size_t)qr * C_DIM + (lane & 7) * 8] = v;
    }
}

// combine -> packed fp8 oatt8 (r17, unchanged)
__global__ void k_att_comb(const short* __restrict__ O0, const short* __restrict__ O1,
                           const float* __restrict__ L0, const float* __restrict__ L1,
                           unsigned char* __restrict__ oatt8) {
    int i = blockIdx.x * 256 + threadIdx.x;
    int row = i >> 6;
    int cidx = i & 63;
    int c0 = cidx * 8;
    float r = 1.0f / (L0[row] + L1[row]);
    size_t base = (size_t)row * C_DIM + c0;
    bf16x8 a = *(const bf16x8*)&O0[base];
    bf16x8 c = *(const bf16x8*)&O1[base];
    float f[8];
    #pragma unroll
    for (int j = 0; j < 8; ++j)
        f[j] = (b2f(a[j]) + b2f(c[j])) * r;
    int lo = __builtin_amdgcn_cvt_pk_fp8_f32(f[0], f[1], 0, false);
    lo     = __builtin_amdgcn_cvt_pk_fp8_f32(f[2], f[3], lo, true);
    int hi = __builtin_amdgcn_cvt_pk_fp8_f32(f[4], f[5], 0, false);
    hi     = __builtin_amdgcn_cvt_pk_fp8_f32(f[6], f[7], hi, true);
    int pbyte = (cidx >> 3) * 64 + (cidx & 3) * 16 + ((cidx >> 2) & 1) * 8;
    *(uint2*)&oatt8[(size_t)row * 512 + pbyte] = make_uint2((unsigned)lo, (unsigned)hi);
}

// ---------------- launch ----------------
extern "C" void kernel_launch(void* const* d_in, const int* in_sizes, int n_in,
                              void* d_out, int out_size, void* d_ws, size_t ws_size,
                              hipStream_t stream) {
    const float* x    = (const float*)d_in[0];
    const float* ln_w = (const float*)d_in[1];
    const float* ln_b = (const float*)d_in[2];
    const float* wq   = (const float*)d_in[3];
    const float* wk   = (const float*)d_in[4];
    const float* wv   = (const float*)d_in[5];
    const float* wp   = (const float*)d_in[6];
    const float* bp   = (const float*)d_in[7];
    float* out = (float*)d_out;

    char* ws = (char*)d_ws;
    size_t off = 0;
    auto alloc = [&](size_t bytes) {
        char* p = ws + off;
        off += (bytes + 255) & ~(size_t)255;
        return p;
    };
    short* hp   = (short*)alloc((size_t)BATCH * PPIX * C_DIM * 2);   // O-partial 0 scratch
    unsigned char* hp8 = (unsigned char*)alloc((size_t)BATCH * PPIX * 512);  // LN out
    unsigned char* wq8 = (unsigned char*)alloc((size_t)512 * 512);
    unsigned char* wk8 = (unsigned char*)alloc((size_t)512 * 4608);
    unsigned char* wv8 = (unsigned char*)alloc((size_t)512 * 4608);
    unsigned char* wp8 = (unsigned char*)alloc((size_t)512 * 512);
    short* qT   = (short*)alloc((size_t)BATCH * HW * C_DIM * 2);
    unsigned char* kT8 = (unsigned char*)alloc((size_t)BATCH * HW * 512);   // K fp8; later oatt8
    short* vg   = (short*)alloc((size_t)BATCH * HW * C_DIM * 2);
    short* oatt = (short*)alloc((size_t)BATCH * HW * C_DIM * 2);     // O-partial 1
    float* mean = (float*)alloc((size_t)BATCH * HW * 4);             // Lsum 0
    float* rstd = (float*)alloc((size_t)BATCH * HW * 4);             // Lsum 1

    hipMemsetAsync(hp8, 0, (size_t)BATCH * PPIX * 512, stream);
    k_reorder_w18<<<128, 256, 0, stream>>>(wq, wq8);
    k_reorder_w18<<<128, 256, 0, stream>>>(wp, wp8);
    k_reorder_w38<<<1152, 256, 0, stream>>>(wk, wk8);
    k_reorder_w38<<<1152, 256, 0, stream>>>(wv, wv8);
    k_ln_fused<<<256, 256, 0, stream>>>(x, ln_w, ln_b, hp8);

    k_gemm_q8<<<512, 256, 0, stream>>>(hp8, wq8, qT);
    k_gemm_kv8<<<512, 256, 0, stream>>>(hp8, wk8, wv8, kT8, vg);

    short* Op0 = hp;
    short* Op1 = oatt;
    float* Ls0 = mean;
    float* Ls1 = rstd;
    k_attn<<<256, 512, 0, stream>>>(qT, kT8, vg, Op0, Op1, Ls0, Ls1);

    // kT8 dead after attn -> reuse as packed fp8 attention output
    unsigned char* oatt8 = kT8;
    k_att_comb<<<4096, 256, 0, stream>>>(Op0, Op1, Ls0, Ls1, oatt8);

    k_gemm_p8<<<512, 256, 0, stream>>>(oatt8, wp8, out, bp, x);
}